// Round 1
// baseline (624.275 us; speedup 1.0000x reference)
//
#include <hip/hip_runtime.h>
#include <hip/hip_bf16.h>

typedef short s16x4 __attribute__((ext_vector_type(4)));
typedef short s16x8 __attribute__((ext_vector_type(8)));
typedef __bf16 bf16x8 __attribute__((ext_vector_type(8)));
typedef float f32x4 __attribute__((ext_vector_type(4)));

#define DEVI static __device__ __forceinline__

DEVI unsigned short f2bf(float x) {
  union { float f; unsigned u; } a; a.f = x;
  unsigned r = a.u + 0x7fffu + ((a.u >> 16) & 1u);
  return (unsigned short)(r >> 16);
}
DEVI float bf2f(unsigned short s) {
  union { unsigned u; float f; } a; a.u = ((unsigned)s) << 16; return a.f;
}
DEVI bf16x8 asbf(s16x8 v) {
  union { s16x8 s; bf16x8 b; } u; u.s = v; return u.b;
}

// ---------------------------------------------------------------------------
// Weight transpose + fp32->bf16 convert: W[1024][1024] (K x N, row-major)
// -> WT[1024][1024] (N x K, row-major, bf16 bits in ushort)
// ---------------------------------------------------------------------------
__global__ __launch_bounds__(256)
void wtrans(const float* __restrict__ W, unsigned short* __restrict__ WT) {
  __shared__ short tile[64][65];
  const int n0 = blockIdx.x * 64;
  const int k0 = blockIdx.y * 64;
  const int t = threadIdx.x;
#pragma unroll
  for (int i = 0; i < 4; i++) {
    int f = t + i * 256;           // float4 index, 16 per row
    int r = f >> 4, c = (f & 15) * 4;
    float4 v = *(const float4*)(W + (size_t)(k0 + r) * 1024 + n0 + c);
    tile[r][c + 0] = (short)f2bf(v.x);
    tile[r][c + 1] = (short)f2bf(v.y);
    tile[r][c + 2] = (short)f2bf(v.z);
    tile[r][c + 3] = (short)f2bf(v.w);
  }
  __syncthreads();
#pragma unroll
  for (int i = 0; i < 2; i++) {
    int f = t + i * 256;           // 8-elem chunk index, 8 per row
    int r = f >> 3, c8 = (f & 7) * 8;
    s16x8 o;
#pragma unroll
    for (int j = 0; j < 8; j++) o[j] = tile[c8 + j][r];
    *(s16x8*)(WT + (size_t)(n0 + r) * 1024 + k0 + c8) = o;
  }
}

// ---------------------------------------------------------------------------
// GEMM: C[orow][n] = A[m][:] @ BT[n][:] + bias[n]
//   A: [M][1024]  (fp32 or bf16 per A_BF16)
//   BT: [1024][1024] bf16 (N x K row-major, i.e. B transposed)
//   output row remap: orow = (m / rpb) * ob + off + (m % rpb)
// Block: 256 thr (4 waves, 2x2), tile 128x128, BK=64.
// ---------------------------------------------------------------------------
template<int A_BF16, int OUT_BF16>
__global__ __launch_bounds__(256)
void gemm_bt(const void* __restrict__ Av, const unsigned short* __restrict__ BT,
             const float* __restrict__ bias, void* __restrict__ Cout,
             int rpb, int ob, int off)
{
  const int K = 1024, N = 1024;
  __shared__ short As[128][72];
  __shared__ short Bs[128][72];
  const int t = threadIdx.x;
  const int lane = t & 63, wid = t >> 6;
  const int wm = wid >> 1, wn = wid & 1;
  const int lr = lane & 15, lg = lane >> 4;
  const size_t m0 = (size_t)blockIdx.y * 128;
  const int n0 = blockIdx.x * 128;

  f32x4 acc[4][4];
#pragma unroll
  for (int i = 0; i < 4; i++)
#pragma unroll
    for (int j = 0; j < 4; j++) acc[i][j] = (f32x4){0.f, 0.f, 0.f, 0.f};

  for (int k0 = 0; k0 < K; k0 += 64) {
    if (A_BF16) {
      const unsigned short* A = (const unsigned short*)Av;
#pragma unroll
      for (int i = 0; i < 4; i++) {
        int f = t + i * 256;
        int r = f >> 3, c = (f & 7) * 8;
        s16x8 v = *(const s16x8*)(A + (m0 + r) * K + k0 + c);
        *(s16x8*)&As[r][c] = v;
      }
    } else {
      const float* A = (const float*)Av;
#pragma unroll
      for (int i = 0; i < 8; i++) {
        int f = t + i * 256;
        int r = f >> 4, c = (f & 15) * 4;
        float4 v = *(const float4*)(A + (m0 + r) * K + k0 + c);
        s16x4 o;
        o[0] = (short)f2bf(v.x); o[1] = (short)f2bf(v.y);
        o[2] = (short)f2bf(v.z); o[3] = (short)f2bf(v.w);
        *(s16x4*)&As[r][c] = o;
      }
    }
#pragma unroll
    for (int i = 0; i < 4; i++) {
      int f = t + i * 256;
      int r = f >> 3, c = (f & 7) * 8;
      s16x8 v = *(const s16x8*)(BT + (size_t)(n0 + r) * K + k0 + c);
      *(s16x8*)&Bs[r][c] = v;
    }
    __syncthreads();
#pragma unroll
    for (int ks = 0; ks < 2; ks++) {
      s16x8 af[4], bfr[4];
#pragma unroll
      for (int i = 0; i < 4; i++)
        af[i] = *(const s16x8*)&As[wm * 64 + i * 16 + lr][ks * 32 + lg * 8];
#pragma unroll
      for (int i = 0; i < 4; i++)
        bfr[i] = *(const s16x8*)&Bs[wn * 64 + i * 16 + lr][ks * 32 + lg * 8];
#pragma unroll
      for (int mi = 0; mi < 4; mi++)
#pragma unroll
        for (int ni = 0; ni < 4; ni++)
          acc[mi][ni] = __builtin_amdgcn_mfma_f32_16x16x32_bf16(
              asbf(af[mi]), asbf(bfr[ni]), acc[mi][ni], 0, 0, 0);
    }
    __syncthreads();
  }

#pragma unroll
  for (int mi = 0; mi < 4; mi++) {
#pragma unroll
    for (int ni = 0; ni < 4; ni++) {
      int cg = n0 + wn * 64 + ni * 16 + lr;
      float bv = bias[cg];
#pragma unroll
      for (int r = 0; r < 4; r++) {
        int rm = (int)m0 + wm * 64 + mi * 16 + lg * 4 + r;
        size_t orow = (size_t)(rm / rpb) * ob + off + (rm % rpb);
        float val = acc[mi][ni][r] + bv;
        if (OUT_BF16) ((unsigned short*)Cout)[orow * N + cg] = f2bf(val);
        else          ((float*)Cout)[orow * N + cg] = val;
      }
    }
  }
}

// ---------------------------------------------------------------------------
// Flash attention.
//   Q:  bf16 [B*2048][1024]   (scaled on load by 1/8)
//   Kb: bf16 [B*2560][1024]   (self keys rows 0..2047, ref keys 2048..2559)
//   Vb: bf16 [B*2560][1024]
//   Y:  bf16 [B*2048][1024]
// Block: 256 thr (4 waves), one (b,h), 64 q-rows (16/wave), 64-key tiles.
// ---------------------------------------------------------------------------
__global__ __launch_bounds__(256)
void attn(const unsigned short* __restrict__ Q, const unsigned short* __restrict__ Kb,
          const unsigned short* __restrict__ Vb, unsigned short* __restrict__ Y)
{
  const int T = 2048, S = 2560, C = 1024, TREF = 512;
  __shared__ short Ks[64][72];
  __shared__ short Vs[64][72];     // transposed: Vs[d][s]
  __shared__ short Ps[4][16][72];  // per-wave P tile
  const int t = threadIdx.x;
  const int lane = t & 63, wid = t >> 6;
  const int lr = lane & 15, lg = lane >> 4;
  const int q0 = blockIdx.x * 64;
  const int bh = blockIdx.y;
  const int b = bh >> 4, h = bh & 15;
  const int hc = h * 64;

  // Q fragments (A layout: row = lane&15, k = (lane>>4)*8+i), pre-scaled 1/8
  s16x8 qf[2];
  {
    size_t qrow = (size_t)(b * T + q0 + wid * 16 + lr);
#pragma unroll
    for (int ks = 0; ks < 2; ks++) {
      s16x8 v = *(const s16x8*)(Q + qrow * C + hc + ks * 32 + lg * 8);
#pragma unroll
      for (int j = 0; j < 8; j++)
        v[j] = (short)f2bf(bf2f((unsigned short)v[j]) * 0.125f);
      qf[ks] = v;
    }
  }

  float m[4], lsum[4];
  f32x4 o[4];
#pragma unroll
  for (int r = 0; r < 4; r++) { m[r] = -1e30f; lsum[r] = 0.f; }
#pragma unroll
  for (int d = 0; d < 4; d++) o[d] = (f32x4){0.f, 0.f, 0.f, 0.f};

  const int self_tiles = q0 / 64 + 1;
  const int ntiles = self_tiles + TREF / 64;

  for (int ti = 0; ti < ntiles; ti++) {
    const int s0 = (ti < self_tiles) ? ti * 64 : T + (ti - self_tiles) * 64;
    const unsigned short* Krow = Kb + (size_t)(b * S + s0) * C + hc;
    const unsigned short* Vrow = Vb + (size_t)(b * S + s0) * C + hc;
    __syncthreads();   // previous tile fully consumed
#pragma unroll
    for (int i = 0; i < 2; i++) {
      int f = t + i * 256;
      int r = f >> 3, c = (f & 7) * 8;
      s16x8 kv = *(const s16x8*)(Krow + (size_t)r * C + c);
      *(s16x8*)&Ks[r][c] = kv;
      s16x8 vv = *(const s16x8*)(Vrow + (size_t)r * C + c);
#pragma unroll
      for (int j = 0; j < 8; j++) Vs[c + j][r] = vv[j];
    }
    __syncthreads();

    // S = Q K^T  (per wave: 16 x 64)
    f32x4 sa[4];
#pragma unroll
    for (int nt = 0; nt < 4; nt++) sa[nt] = (f32x4){0.f, 0.f, 0.f, 0.f};
#pragma unroll
    for (int ks = 0; ks < 2; ks++)
#pragma unroll
      for (int nt = 0; nt < 4; nt++) {
        s16x8 kb2 = *(const s16x8*)&Ks[nt * 16 + lr][ks * 32 + lg * 8];
        sa[nt] = __builtin_amdgcn_mfma_f32_16x16x32_bf16(
            asbf(qf[ks]), asbf(kb2), sa[nt], 0, 0, 0);
      }

    // causal mask on partial self tiles
    if (ti < self_tiles && s0 + 63 > q0) {
#pragma unroll
      for (int nt = 0; nt < 4; nt++)
#pragma unroll
        for (int r = 0; r < 4; r++) {
          int qg = q0 + wid * 16 + lg * 4 + r;
          int sg = s0 + nt * 16 + lr;
          if (sg > qg) sa[nt][r] = -1e30f;
        }
    }

    // online softmax (rows live on 16-lane groups)
    float p[4][4];
#pragma unroll
    for (int r = 0; r < 4; r++) {
      float tm = fmaxf(fmaxf(sa[0][r], sa[1][r]), fmaxf(sa[2][r], sa[3][r]));
#pragma unroll
      for (int msk = 1; msk < 16; msk <<= 1) tm = fmaxf(tm, __shfl_xor(tm, msk, 64));
      float mn = fmaxf(m[r], tm);
      float alpha = __expf(m[r] - mn);
      float rs = 0.f;
#pragma unroll
      for (int nt = 0; nt < 4; nt++) {
        float pv = __expf(sa[nt][r] - mn);
        p[nt][r] = pv; rs += pv;
      }
#pragma unroll
      for (int msk = 1; msk < 16; msk <<= 1) rs += __shfl_xor(rs, msk, 64);
      lsum[r] = lsum[r] * alpha + rs;
      m[r] = mn;
#pragma unroll
      for (int d = 0; d < 4; d++) o[d][r] *= alpha;
    }

    // P -> LDS (reshape to A-fragment layout), then O += P @ V
#pragma unroll
    for (int nt = 0; nt < 4; nt++)
#pragma unroll
      for (int r = 0; r < 4; r++)
        Ps[wid][lg * 4 + r][nt * 16 + lr] = (short)f2bf(p[nt][r]);

#pragma unroll
    for (int ks = 0; ks < 2; ks++) {
      s16x8 pa = *(const s16x8*)&Ps[wid][lr][ks * 32 + lg * 8];
#pragma unroll
      for (int dt = 0; dt < 4; dt++) {
        s16x8 vb2 = *(const s16x8*)&Vs[dt * 16 + lr][ks * 32 + lg * 8];
        o[dt] = __builtin_amdgcn_mfma_f32_16x16x32_bf16(
            asbf(pa), asbf(vb2), o[dt], 0, 0, 0);
      }
    }
  }

  // epilogue: Y = O / lsum  (bf16)
#pragma unroll
  for (int r = 0; r < 4; r++) {
    float inv = 1.0f / lsum[r];
    size_t qrow = (size_t)(b * T + q0 + wid * 16 + lg * 4 + r);
#pragma unroll
    for (int dt = 0; dt < 4; dt++)
      Y[qrow * C + hc + dt * 16 + lr] = f2bf(o[dt][r] * inv);
  }
}

// ---------------------------------------------------------------------------
extern "C" void kernel_launch(void* const* d_in, const int* in_sizes, int n_in,
                              void* d_out, int out_size, void* d_ws, size_t ws_size,
                              hipStream_t stream) {
  const float* x   = (const float*)d_in[0];
  const float* ref = (const float*)d_in[1];
  const float* Wq  = (const float*)d_in[2];
  const float* bq  = (const float*)d_in[3];
  const float* Wk  = (const float*)d_in[4];
  const float* bk  = (const float*)d_in[5];
  const float* Wv  = (const float*)d_in[6];
  const float* bv  = (const float*)d_in[7];
  const float* Wrk = (const float*)d_in[8];
  const float* brk = (const float*)d_in[9];
  const float* Wrv = (const float*)d_in[10];
  const float* brv = (const float*)d_in[11];
  const float* Wp  = (const float*)d_in[12];
  const float* bp  = (const float*)d_in[13];
  float* out = (float*)d_out;

  char* ws = (char*)d_ws;
  auto alloc = [&](size_t bytes) {
    char* p = ws; ws += (bytes + 255) & ~(size_t)255; return p;
  };
  const size_t WB = (size_t)1024 * 1024 * 2;
  unsigned short* WqT  = (unsigned short*)alloc(WB);
  unsigned short* WkT  = (unsigned short*)alloc(WB);
  unsigned short* WvT  = (unsigned short*)alloc(WB);
  unsigned short* WrkT = (unsigned short*)alloc(WB);
  unsigned short* WrvT = (unsigned short*)alloc(WB);
  unsigned short* WpT  = (unsigned short*)alloc(WB);
  unsigned short* qb = (unsigned short*)alloc((size_t)8192 * 1024 * 2);
  unsigned short* kb = (unsigned short*)alloc((size_t)4 * 2560 * 1024 * 2);
  unsigned short* vb = (unsigned short*)alloc((size_t)4 * 2560 * 1024 * 2);
  unsigned short* yb = (unsigned short*)alloc((size_t)8192 * 1024 * 2);

  dim3 tb(256);
  dim3 tg(16, 16);
  wtrans<<<tg, tb, 0, stream>>>(Wq,  WqT);
  wtrans<<<tg, tb, 0, stream>>>(Wk,  WkT);
  wtrans<<<tg, tb, 0, stream>>>(Wv,  WvT);
  wtrans<<<tg, tb, 0, stream>>>(Wrk, WrkT);
  wtrans<<<tg, tb, 0, stream>>>(Wrv, WrvT);
  wtrans<<<tg, tb, 0, stream>>>(Wp,  WpT);

  dim3 gq(8, 64);   // N/128, M/128 for M=8192
  dim3 gr(8, 16);   // M=2048
  gemm_bt<0, 1><<<gq, tb, 0, stream>>>(x,   WqT,  bq,  qb, 8192, 8192, 0);
  gemm_bt<0, 1><<<gq, tb, 0, stream>>>(x,   WkT,  bk,  kb, 2048, 2560, 0);
  gemm_bt<0, 1><<<gq, tb, 0, stream>>>(x,   WvT,  bv,  vb, 2048, 2560, 0);
  gemm_bt<0, 1><<<gr, tb, 0, stream>>>(ref, WrkT, brk, kb, 512,  2560, 2048);
  gemm_bt<0, 1><<<gr, tb, 0, stream>>>(ref, WrvT, brv, vb, 512,  2560, 2048);

  dim3 ga(32, 64);  // T/64, B*H
  attn<<<ga, tb, 0, stream>>>(qb, kb, vb, yb);

  gemm_bt<1, 0><<<gq, tb, 0, stream>>>(yb, WpT, bp, out, 8192, 8192, 0);
}

// Round 2
// 500.991 us; speedup vs baseline: 1.2461x; 1.2461x over previous
//
#include <hip/hip_runtime.h>
#include <hip/hip_bf16.h>

typedef short s16x4 __attribute__((ext_vector_type(4)));
typedef short s16x8 __attribute__((ext_vector_type(8)));
typedef __bf16 bf16x8 __attribute__((ext_vector_type(8)));
typedef float f32x4 __attribute__((ext_vector_type(4)));

#define DEVI static __device__ __forceinline__

DEVI unsigned short f2bf(float x) {
  union { float f; unsigned u; } a; a.f = x;
  unsigned r = a.u + 0x7fffu + ((a.u >> 16) & 1u);
  return (unsigned short)(r >> 16);
}
DEVI float bf2f(unsigned short s) {
  union { unsigned u; float f; } a; a.u = ((unsigned)s) << 16; return a.f;
}
DEVI bf16x8 asbf(s16x8 v) {
  union { s16x8 s; bf16x8 b; } u; u.s = v; return u.b;
}

// ---------------------------------------------------------------------------
// Weight transpose + fp32->bf16: W[1024][1024] (KxN) -> WT[1024][1024] (NxK)
// ---------------------------------------------------------------------------
__global__ __launch_bounds__(256)
void wtrans(const float* __restrict__ W, unsigned short* __restrict__ WT) {
  __shared__ short tile[64][65];
  const int n0 = blockIdx.x * 64;
  const int k0 = blockIdx.y * 64;
  const int t = threadIdx.x;
#pragma unroll
  for (int i = 0; i < 4; i++) {
    int f = t + i * 256;
    int r = f >> 4, c = (f & 15) * 4;
    float4 v = *(const float4*)(W + (size_t)(k0 + r) * 1024 + n0 + c);
    tile[r][c + 0] = (short)f2bf(v.x);
    tile[r][c + 1] = (short)f2bf(v.y);
    tile[r][c + 2] = (short)f2bf(v.z);
    tile[r][c + 3] = (short)f2bf(v.w);
  }
  __syncthreads();
#pragma unroll
  for (int i = 0; i < 2; i++) {
    int f = t + i * 256;
    int r = f >> 3, c8 = (f & 7) * 8;
    s16x8 o;
#pragma unroll
    for (int j = 0; j < 8; j++) o[j] = tile[c8 + j][r];
    *(s16x8*)(WT + (size_t)(n0 + r) * 1024 + k0 + c8) = o;
  }
}

// ---------------------------------------------------------------------------
// GEMM: C[orow][n] = A[m][:] @ BT[n][:] + bias[n]
// 128x128 tile, BK=64, 4 waves; XOR-swizzled LDS (stride 64, blk ^= row&7).
// ---------------------------------------------------------------------------
template<int A_BF16, int OUT_BF16>
__global__ __launch_bounds__(256)
void gemm_bt(const void* __restrict__ Av, const unsigned short* __restrict__ BT,
             const float* __restrict__ bias, void* __restrict__ Cout,
             int rpb, int ob, int off)
{
  const int K = 1024, N = 1024;
  __shared__ short As[128][64];
  __shared__ short Bs[128][64];
  const int t = threadIdx.x;
  const int lane = t & 63, wid = t >> 6;
  const int wm = wid >> 1, wn = wid & 1;
  const int lr = lane & 15, lg = lane >> 4;
  const size_t m0 = (size_t)blockIdx.y * 128;
  const int n0 = blockIdx.x * 128;

  f32x4 acc[4][4];
#pragma unroll
  for (int i = 0; i < 4; i++)
#pragma unroll
    for (int j = 0; j < 4; j++) acc[i][j] = (f32x4){0.f, 0.f, 0.f, 0.f};

  for (int k0 = 0; k0 < K; k0 += 64) {
    if (A_BF16) {
      const unsigned short* A = (const unsigned short*)Av;
#pragma unroll
      for (int i = 0; i < 4; i++) {
        int f = t + i * 256;
        int r = f >> 3, cb = f & 7;
        s16x8 v = *(const s16x8*)(A + (m0 + r) * K + k0 + cb * 8);
        *(s16x8*)&As[r][((cb ^ r) & 7) * 8] = v;
      }
    } else {
      const float* A = (const float*)Av;
#pragma unroll
      for (int i = 0; i < 8; i++) {
        int f = t + i * 256;
        int r = f >> 4, c = (f & 15) * 4;
        float4 v = *(const float4*)(A + (m0 + r) * K + k0 + c);
        s16x4 o;
        o[0] = (short)f2bf(v.x); o[1] = (short)f2bf(v.y);
        o[2] = (short)f2bf(v.z); o[3] = (short)f2bf(v.w);
        int cb = (f & 15) >> 1;
        *(s16x4*)&As[r][((cb ^ r) & 7) * 8 + (f & 1) * 4] = o;
      }
    }
#pragma unroll
    for (int i = 0; i < 4; i++) {
      int f = t + i * 256;
      int r = f >> 3, cb = f & 7;
      s16x8 v = *(const s16x8*)(BT + (size_t)(n0 + r) * K + k0 + cb * 8);
      *(s16x8*)&Bs[r][((cb ^ r) & 7) * 8] = v;
    }
    __syncthreads();
#pragma unroll
    for (int ks = 0; ks < 2; ks++) {
      s16x8 af[4], bfr[4];
#pragma unroll
      for (int i = 0; i < 4; i++)
        af[i] = *(const s16x8*)&As[wm * 64 + i * 16 + lr][(((ks * 4 + lg) ^ lr) & 7) * 8];
#pragma unroll
      for (int i = 0; i < 4; i++)
        bfr[i] = *(const s16x8*)&Bs[wn * 64 + i * 16 + lr][(((ks * 4 + lg) ^ lr) & 7) * 8];
#pragma unroll
      for (int mi = 0; mi < 4; mi++)
#pragma unroll
        for (int ni = 0; ni < 4; ni++)
          acc[mi][ni] = __builtin_amdgcn_mfma_f32_16x16x32_bf16(
              asbf(af[mi]), asbf(bfr[ni]), acc[mi][ni], 0, 0, 0);
    }
    __syncthreads();
  }

#pragma unroll
  for (int mi = 0; mi < 4; mi++) {
#pragma unroll
    for (int ni = 0; ni < 4; ni++) {
      int cg = n0 + wn * 64 + ni * 16 + lr;
      float bv = bias[cg];
#pragma unroll
      for (int r = 0; r < 4; r++) {
        int rm = (int)m0 + wm * 64 + mi * 16 + lg * 4 + r;
        size_t orow = (size_t)(rm / rpb) * ob + off + (rm % rpb);
        float val = acc[mi][ni][r] + bv;
        if (OUT_BF16) ((unsigned short*)Cout)[orow * N + cg] = f2bf(val);
        else          ((float*)Cout)[orow * N + cg] = val;
      }
    }
  }
}

// ---------------------------------------------------------------------------
// Flash attention, v2: swizzled LDS, global-transposed V, double-buffered
// staging with async split, 1 barrier/tile.
//   Q: bf16 [B*2048][1024]; Kb,Vb: bf16 [B*2560][1024]; Y: bf16 [B*2048][1024]
// Block: 256 thr (4 waves), one (b,h), 64 q-rows, 64-key tiles.
// ---------------------------------------------------------------------------
__global__ __launch_bounds__(256, 4)
void attn(const unsigned short* __restrict__ Q, const unsigned short* __restrict__ Kb,
          const unsigned short* __restrict__ Vb, unsigned short* __restrict__ Y)
{
  const int T = 2048, S = 2560, C = 1024, TREF = 512;
  __shared__ short Ks[2][64][64];
  __shared__ short Vt[2][64][64];   // transposed: Vt[d][s]
  __shared__ short Ps[4][16][64];   // per-wave P tile
  const int t = threadIdx.x;
  const int lane = t & 63, wid = t >> 6;
  const int lr = lane & 15, lg = lane >> 4;
  const int q0 = blockIdx.x * 64;
  const int bh = blockIdx.y;
  const int b = bh >> 4, h = bh & 15;
  const int hc = h * 64;

  // Q fragments (A layout: row = lane&15, k = (lane>>4)*8+j), pre-scaled 1/8
  s16x8 qf[2];
  {
    size_t qrow = (size_t)(b * T + q0 + wid * 16 + lr);
#pragma unroll
    for (int ks = 0; ks < 2; ks++) {
      s16x8 v = *(const s16x8*)(Q + qrow * C + hc + ks * 32 + lg * 8);
#pragma unroll
      for (int j = 0; j < 8; j++)
        v[j] = (short)f2bf(bf2f((unsigned short)v[j]) * 0.125f);
      qf[ks] = v;
    }
  }

  float m[4], lsum[4];
  f32x4 o[4];
#pragma unroll
  for (int r = 0; r < 4; r++) { m[r] = -1e30f; lsum[r] = 0.f; }
#pragma unroll
  for (int d = 0; d < 4; d++) o[d] = (f32x4){0.f, 0.f, 0.f, 0.f};

  const int self_tiles = blockIdx.x + 1;
  const int ntiles = self_tiles + TREF / 64;

  // staging state
  const int kr0 = t >> 3, kcb = t & 7;   // K: rows kr0 / kr0+32, col-block kcb
  const int vd = lane;                   // V: transposed row (d), per wave
  s16x8 kreg[2];
  unsigned short vld[16];

  auto s0_of = [&](int ti2) {
    return (ti2 < self_tiles) ? ti2 * 64 : T + (ti2 - self_tiles) * 64;
  };
  auto load_tile = [&](int ti2) {
    int s0 = s0_of(ti2);
    const unsigned short* Krow = Kb + (size_t)(b * S + s0) * C + hc;
    const unsigned short* Vrow = Vb + (size_t)(b * S + s0) * C + hc;
    kreg[0] = *(const s16x8*)(Krow + (size_t)kr0 * C + kcb * 8);
    kreg[1] = *(const s16x8*)(Krow + (size_t)(kr0 + 32) * C + kcb * 8);
#pragma unroll
    for (int half = 0; half < 2; half++) {
      int sl = (wid + half * 4) * 8;
#pragma unroll
      for (int j = 0; j < 8; j++)
        vld[half * 8 + j] = Vrow[(size_t)(sl + j) * C + vd];
    }
  };
  auto write_tile = [&](int buf) {
    *(s16x8*)&Ks[buf][kr0][((kcb ^ kr0) & 7) * 8] = kreg[0];
    *(s16x8*)&Ks[buf][kr0 + 32][((kcb ^ (kr0 + 32)) & 7) * 8] = kreg[1];
#pragma unroll
    for (int half = 0; half < 2; half++) {
      int4 pk;
      pk.x = (unsigned)vld[half * 8 + 0] | ((unsigned)vld[half * 8 + 1] << 16);
      pk.y = (unsigned)vld[half * 8 + 2] | ((unsigned)vld[half * 8 + 3] << 16);
      pk.z = (unsigned)vld[half * 8 + 4] | ((unsigned)vld[half * 8 + 5] << 16);
      pk.w = (unsigned)vld[half * 8 + 6] | ((unsigned)vld[half * 8 + 7] << 16);
      *(int4*)&Vt[buf][vd][(((wid + half * 4) ^ vd) & 7) * 8] = pk;
    }
  };

  load_tile(0);
  write_tile(0);
  __syncthreads();

  for (int ti = 0; ti < ntiles; ti++) {
    const int cur = ti & 1;
    const bool more = (ti + 1 < ntiles);
    const int s0 = s0_of(ti);
    if (more) load_tile(ti + 1);   // async: issue global loads early

    // ---- S = Q K^T (per wave: 16 q x 64 s) ----
    f32x4 sa[4];
#pragma unroll
    for (int nt = 0; nt < 4; nt++) sa[nt] = (f32x4){0.f, 0.f, 0.f, 0.f};
#pragma unroll
    for (int ks = 0; ks < 2; ks++)
#pragma unroll
      for (int nt = 0; nt < 4; nt++) {
        s16x8 kb2 = *(const s16x8*)&Ks[cur][nt * 16 + lr][(((ks * 4 + lg) ^ lr) & 7) * 8];
        sa[nt] = __builtin_amdgcn_mfma_f32_16x16x32_bf16(
            asbf(qf[ks]), asbf(kb2), sa[nt], 0, 0, 0);
      }

    // causal mask on the diagonal self tile
    if (ti == self_tiles - 1 && s0 < T) {
#pragma unroll
      for (int nt = 0; nt < 4; nt++)
#pragma unroll
        for (int r = 0; r < 4; r++) {
          int qg = q0 + wid * 16 + lg * 4 + r;
          int sg = s0 + nt * 16 + lr;
          if (sg > qg) sa[nt][r] = -1e30f;
        }
    }

    // ---- online softmax (rows on 16-lane groups) ----
    float p[4][4];
#pragma unroll
    for (int r = 0; r < 4; r++) {
      float tm = fmaxf(fmaxf(sa[0][r], sa[1][r]), fmaxf(sa[2][r], sa[3][r]));
#pragma unroll
      for (int msk = 1; msk < 16; msk <<= 1) tm = fmaxf(tm, __shfl_xor(tm, msk, 64));
      float mn = fmaxf(m[r], tm);
      float alpha = __expf(m[r] - mn);
      float rs = 0.f;
#pragma unroll
      for (int nt = 0; nt < 4; nt++) {
        float pv = __expf(sa[nt][r] - mn);
        p[nt][r] = pv; rs += pv;
      }
#pragma unroll
      for (int msk = 1; msk < 16; msk <<= 1) rs += __shfl_xor(rs, msk, 64);
      lsum[r] = lsum[r] * alpha + rs;
      m[r] = mn;
#pragma unroll
      for (int d = 0; d < 4; d++) o[d][r] *= alpha;
    }

    // ---- P -> LDS (swizzled), then O += P @ V ----
#pragma unroll
    for (int nt = 0; nt < 4; nt++)
#pragma unroll
      for (int r = 0; r < 4; r++) {
        int row = lg * 4 + r, col = nt * 16 + lr;
        Ps[wid][row][(((col >> 3) ^ row) & 7) * 8 + (col & 7)] = (short)f2bf(p[nt][r]);
      }

#pragma unroll
    for (int ks = 0; ks < 2; ks++) {
      s16x8 pa = *(const s16x8*)&Ps[wid][lr][(((ks * 4 + lg) ^ lr) & 7) * 8];
#pragma unroll
      for (int dt = 0; dt < 4; dt++) {
        s16x8 vb2 = *(const s16x8*)&Vt[cur][dt * 16 + lr][(((ks * 4 + lg) ^ lr) & 7) * 8];
        o[dt] = __builtin_amdgcn_mfma_f32_16x16x32_bf16(
            asbf(pa), asbf(vb2), o[dt], 0, 0, 0);
      }
    }

    if (more) write_tile(cur ^ 1);  // lands just before the barrier
    __syncthreads();
  }

  // epilogue: Y = O / lsum  (bf16)
#pragma unroll
  for (int r = 0; r < 4; r++) {
    float inv = 1.0f / lsum[r];
    size_t qrow = (size_t)(b * T + q0 + wid * 16 + lg * 4 + r);
#pragma unroll
    for (int dt = 0; dt < 4; dt++)
      Y[qrow * C + hc + dt * 16 + lr] = f2bf(o[dt][r] * inv);
  }
}

// ---------------------------------------------------------------------------
extern "C" void kernel_launch(void* const* d_in, const int* in_sizes, int n_in,
                              void* d_out, int out_size, void* d_ws, size_t ws_size,
                              hipStream_t stream) {
  const float* x   = (const float*)d_in[0];
  const float* ref = (const float*)d_in[1];
  const float* Wq  = (const float*)d_in[2];
  const float* bq  = (const float*)d_in[3];
  const float* Wk  = (const float*)d_in[4];
  const float* bk  = (const float*)d_in[5];
  const float* Wv  = (const float*)d_in[6];
  const float* bv  = (const float*)d_in[7];
  const float* Wrk = (const float*)d_in[8];
  const float* brk = (const float*)d_in[9];
  const float* Wrv = (const float*)d_in[10];
  const float* brv = (const float*)d_in[11];
  const float* Wp  = (const float*)d_in[12];
  const float* bp  = (const float*)d_in[13];
  float* out = (float*)d_out;

  char* ws = (char*)d_ws;
  auto alloc = [&](size_t bytes) {
    char* p = ws; ws += (bytes + 255) & ~(size_t)255; return p;
  };
  const size_t WB = (size_t)1024 * 1024 * 2;
  unsigned short* WqT  = (unsigned short*)alloc(WB);
  unsigned short* WkT  = (unsigned short*)alloc(WB);
  unsigned short* WvT  = (unsigned short*)alloc(WB);
  unsigned short* WrkT = (unsigned short*)alloc(WB);
  unsigned short* WrvT = (unsigned short*)alloc(WB);
  unsigned short* WpT  = (unsigned short*)alloc(WB);
  unsigned short* qb = (unsigned short*)alloc((size_t)8192 * 1024 * 2);
  unsigned short* kb = (unsigned short*)alloc((size_t)4 * 2560 * 1024 * 2);
  unsigned short* vb = (unsigned short*)alloc((size_t)4 * 2560 * 1024 * 2);
  unsigned short* yb = (unsigned short*)alloc((size_t)8192 * 1024 * 2);

  dim3 tb(256);
  dim3 tg(16, 16);
  wtrans<<<tg, tb, 0, stream>>>(Wq,  WqT);
  wtrans<<<tg, tb, 0, stream>>>(Wk,  WkT);
  wtrans<<<tg, tb, 0, stream>>>(Wv,  WvT);
  wtrans<<<tg, tb, 0, stream>>>(Wrk, WrkT);
  wtrans<<<tg, tb, 0, stream>>>(Wrv, WrvT);
  wtrans<<<tg, tb, 0, stream>>>(Wp,  WpT);

  dim3 gq(8, 64);   // N/128, M/128 for M=8192
  dim3 gr(8, 16);   // M=2048
  gemm_bt<0, 1><<<gq, tb, 0, stream>>>(x,   WqT,  bq,  qb, 8192, 8192, 0);
  gemm_bt<0, 1><<<gq, tb, 0, stream>>>(x,   WkT,  bk,  kb, 2048, 2560, 0);
  gemm_bt<0, 1><<<gq, tb, 0, stream>>>(x,   WvT,  bv,  vb, 2048, 2560, 0);
  gemm_bt<0, 1><<<gr, tb, 0, stream>>>(ref, WrkT, brk, kb, 512,  2560, 2048);
  gemm_bt<0, 1><<<gr, tb, 0, stream>>>(ref, WrvT, brv, vb, 512,  2560, 2048);

  dim3 ga(32, 64);  // T/64, B*H
  attn<<<ga, tb, 0, stream>>>(qb, kb, vb, yb);

  gemm_bt<1, 0><<<gq, tb, 0, stream>>>(yb, WpT, bp, out, 8192, 8192, 0);
}

// Round 3
// 321.577 us; speedup vs baseline: 1.9413x; 1.5579x over previous
//
#include <hip/hip_runtime.h>
#include <hip/hip_bf16.h>

typedef short s16x4 __attribute__((ext_vector_type(4)));
typedef short s16x8 __attribute__((ext_vector_type(8)));
typedef __bf16 bf16x8 __attribute__((ext_vector_type(8)));
typedef float f32x4 __attribute__((ext_vector_type(4)));

#define DEVI static __device__ __forceinline__

DEVI unsigned short f2bf(float x) {
  union { float f; unsigned u; } a; a.f = x;
  unsigned r = a.u + 0x7fffu + ((a.u >> 16) & 1u);
  return (unsigned short)(r >> 16);
}
DEVI float bf2f(unsigned short s) {
  union { unsigned u; float f; } a; a.u = ((unsigned)s) << 16; return a.f;
}
DEVI bf16x8 asbf(s16x8 v) {
  union { s16x8 s; bf16x8 b; } u; u.s = v; return u.b;
}
DEVI void gload16(const void* g, void* l) {
  __builtin_amdgcn_global_load_lds(
      (const __attribute__((address_space(1))) void*)g,
      (__attribute__((address_space(3))) void*)l, 16, 0, 0);
}

// ---------------------------------------------------------------------------
// Weight transpose + fp32->bf16, PRE-SWIZZLED for linear global_load_lds:
// W[1024][1024] (KxN) -> WTg[n][k0 + ((c8 ^ (n&7))&7)*8 + j] = W[k0+c8*8+j][n]
// ---------------------------------------------------------------------------
__global__ __launch_bounds__(256)
void wtrans(const float* __restrict__ W, unsigned short* __restrict__ WT) {
  __shared__ short tile[64][65];
  const int n0 = blockIdx.x * 64;
  const int k0 = blockIdx.y * 64;
  const int t = threadIdx.x;
#pragma unroll
  for (int i = 0; i < 4; i++) {
    int f = t + i * 256;
    int r = f >> 4, c = (f & 15) * 4;
    float4 v = *(const float4*)(W + (size_t)(k0 + r) * 1024 + n0 + c);
    tile[r][c + 0] = (short)f2bf(v.x);
    tile[r][c + 1] = (short)f2bf(v.y);
    tile[r][c + 2] = (short)f2bf(v.z);
    tile[r][c + 3] = (short)f2bf(v.w);
  }
  __syncthreads();
#pragma unroll
  for (int i = 0; i < 2; i++) {
    int f = t + i * 256;
    int r = f >> 3, c8 = f & 7;
    s16x8 o;
#pragma unroll
    for (int j = 0; j < 8; j++) o[j] = tile[c8 * 8 + j][r];
    *(s16x8*)(WT + (size_t)(n0 + r) * 1024 + k0 + ((c8 ^ (r & 7)) & 7) * 8) = o;
  }
}

// ---------------------------------------------------------------------------
// fp32 -> bf16 convert, pre-swizzled by row (within 64-col K-tiles).
// ---------------------------------------------------------------------------
__global__ __launch_bounds__(256)
void convswz(const float* __restrict__ X, unsigned short* __restrict__ Xg) {
  int f = blockIdx.x * 256 + threadIdx.x;
  int row = f >> 7, c8 = f & 127;
  const float* src = X + (size_t)row * 1024 + c8 * 8;
  float4 a = *(const float4*)src;
  float4 b2 = *(const float4*)(src + 4);
  s16x8 o;
  o[0] = (short)f2bf(a.x);  o[1] = (short)f2bf(a.y);
  o[2] = (short)f2bf(a.z);  o[3] = (short)f2bf(a.w);
  o[4] = (short)f2bf(b2.x); o[5] = (short)f2bf(b2.y);
  o[6] = (short)f2bf(b2.z); o[7] = (short)f2bf(b2.w);
  int cs = (c8 & ~7) | ((c8 ^ row) & 7);
  *(s16x8*)(Xg + (size_t)row * 1024 + cs * 8) = o;
}

// ---------------------------------------------------------------------------
// GEMM: A (bf16, pre-swizzled) @ BT (bf16, pre-swizzled) + bias.
// 128x128 tile, BK=64, 4 waves; global_load_lds width-16 staging (m97).
// MODE 0: QKV fused (N=3072) -> qb | kb(swz) | vb.  rows: batch of 2048.
// MODE 1: refKV fused (N=2048) -> kb(swz) | vb at +2048. rows: batch of 512.
// MODE 2: proj (N=1024) -> fp32 out.
// ---------------------------------------------------------------------------
template<int MODE>
__global__ __launch_bounds__(256)
void gemm_bt(const unsigned short* __restrict__ A, const unsigned short* __restrict__ BT,
             const float* __restrict__ b0, const float* __restrict__ b1,
             const float* __restrict__ b2,
             void* __restrict__ o0, void* __restrict__ o1, void* __restrict__ o2)
{
  const int K = 1024;
  __shared__ __align__(16) short As[128][64];
  __shared__ __align__(16) short Bs[128][64];
  const int t = threadIdx.x;
  const int lane = t & 63, wid = t >> 6;
  const int wm = wid >> 1, wn = wid & 1;
  const int lr = lane & 15, lg = lane >> 4;
  const size_t m0 = (size_t)blockIdx.y * 128;
  const int n0 = blockIdx.x * 128;

  f32x4 acc[4][4];
#pragma unroll
  for (int i = 0; i < 4; i++)
#pragma unroll
    for (int j = 0; j < 4; j++) acc[i][j] = (f32x4){0.f, 0.f, 0.f, 0.f};

  const unsigned short* Abase = A + m0 * K;
  const unsigned short* Bbase = BT + (size_t)n0 * K;
  const int r_ld = t >> 3, cb_ld = t & 7;

  for (int k0 = 0; k0 < K; k0 += 64) {
#pragma unroll
    for (int i = 0; i < 4; i++) {
      int r = r_ld + i * 32;
      gload16(Abase + (size_t)r * K + k0 + cb_ld * 8,
              (short*)As + (i * 256 + wid * 64) * 8);
      gload16(Bbase + (size_t)r * K + k0 + cb_ld * 8,
              (short*)Bs + (i * 256 + wid * 64) * 8);
    }
    __syncthreads();
#pragma unroll
    for (int ks = 0; ks < 2; ks++) {
      s16x8 af[4], bfr[4];
#pragma unroll
      for (int i = 0; i < 4; i++)
        af[i] = *(const s16x8*)&As[wm * 64 + i * 16 + lr][(((ks * 4 + lg) ^ lr) & 7) * 8];
#pragma unroll
      for (int i = 0; i < 4; i++)
        bfr[i] = *(const s16x8*)&Bs[wn * 64 + i * 16 + lr][(((ks * 4 + lg) ^ lr) & 7) * 8];
#pragma unroll
      for (int mi = 0; mi < 4; mi++)
#pragma unroll
        for (int ni = 0; ni < 4; ni++)
          acc[mi][ni] = __builtin_amdgcn_mfma_f32_16x16x32_bf16(
              asbf(af[mi]), asbf(bfr[ni]), acc[mi][ni], 0, 0, 0);
    }
    __syncthreads();
  }

  const int seg = n0 >> 10;
  const float* bb = (seg == 0) ? b0 : (seg == 1 ? b1 : b2);
#pragma unroll
  for (int mi = 0; mi < 4; mi++) {
#pragma unroll
    for (int ni = 0; ni < 4; ni++) {
      int cg = n0 + wn * 64 + ni * 16 + lr;
      int c = cg & 1023;
      float bv = bb[c];
#pragma unroll
      for (int r = 0; r < 4; r++) {
        int rm = (int)m0 + wm * 64 + mi * 16 + lg * 4 + r;
        float val = acc[mi][ni][r] + bv;
        if (MODE == 2) {
          ((float*)o0)[(size_t)rm * 1024 + cg] = val;
        } else {
          size_t orow; unsigned short* dst; bool swz;
          if (MODE == 0) {
            if (seg == 0) { dst = (unsigned short*)o0; orow = rm; swz = false; }
            else {
              orow = (size_t)(rm >> 11) * 2560 + (rm & 2047);
              dst = (unsigned short*)(seg == 1 ? o1 : o2); swz = (seg == 1);
            }
          } else {
            orow = (size_t)(rm >> 9) * 2560 + 2048 + (rm & 511);
            dst = (unsigned short*)(seg == 0 ? o0 : o1); swz = (seg == 0);
          }
          int cc = c;
          if (swz) cc = (c & ~63) | ((((c >> 3) ^ (int)orow) & 7) << 3) | (c & 7);
          dst[orow * 1024 + cc] = f2bf(val);
        }
      }
    }
  }
}

// ---------------------------------------------------------------------------
// Flash attention v3: gload_lds K staging (kb pre-swizzled), defer-max,
// per-lane partial softmax sum, exp2 domain, swizzled yb output.
// ---------------------------------------------------------------------------
__global__ __launch_bounds__(256, 4)
void attn(const unsigned short* __restrict__ Q, const unsigned short* __restrict__ Kb,
          const unsigned short* __restrict__ Vb, unsigned short* __restrict__ Y)
{
  const int T = 2048, S = 2560, C = 1024, TREF = 512;
  __shared__ __align__(16) short Ks[2][64][64];
  __shared__ __align__(16) short Vt[2][64][64];   // transposed: Vt[d][s]
  __shared__ __align__(16) short Ps[4][16][64];
  const int t = threadIdx.x;
  const int lane = t & 63, wid = t >> 6;
  const int lr = lane & 15, lg = lane >> 4;
  const int q0 = blockIdx.x * 64;
  const int bh = blockIdx.y;
  const int b = bh >> 4, h = bh & 15;
  const int hc = h * 64;

  // Q fragments, pre-scaled by (1/8)*log2(e) -> softmax in exp2 domain
  const float QSC = 0.125f * 1.44269504088896f;
  s16x8 qf[2];
  {
    size_t qrow = (size_t)(b * T + q0 + wid * 16 + lr);
#pragma unroll
    for (int ks = 0; ks < 2; ks++) {
      s16x8 v = *(const s16x8*)(Q + qrow * C + hc + ks * 32 + lg * 8);
#pragma unroll
      for (int j = 0; j < 8; j++)
        v[j] = (short)f2bf(bf2f((unsigned short)v[j]) * QSC);
      qf[ks] = v;
    }
  }

  float m[4], lsum[4];
  f32x4 o[4];
#pragma unroll
  for (int r = 0; r < 4; r++) { m[r] = -1e30f; lsum[r] = 0.f; }
#pragma unroll
  for (int d = 0; d < 4; d++) o[d] = (f32x4){0.f, 0.f, 0.f, 0.f};

  const int self_tiles = blockIdx.x + 1;
  const int ntiles = self_tiles + TREF / 64;

  const int vd = lane;
  unsigned short vld[16];

  auto s0_of = [&](int ti2) {
    return (ti2 < self_tiles) ? ti2 * 64 : T + (ti2 - self_tiles) * 64;
  };
  auto load_K = [&](int ti2, int buf) {   // kb is pre-swizzled -> linear LDS
    int s0 = s0_of(ti2);
    const unsigned short* Krow = Kb + (size_t)(b * S + s0) * C + hc;
#pragma unroll
    for (int i = 0; i < 2; i++) {
      int r = (t >> 3) + i * 32, cb = t & 7;
      gload16(Krow + (size_t)r * C + cb * 8,
              (short*)&Ks[buf][0][0] + (i * 256 + wid * 64) * 8);
    }
  };
  auto load_V = [&](int ti2) {
    int s0 = s0_of(ti2);
    const unsigned short* Vrow = Vb + (size_t)(b * S + s0) * C + hc;
#pragma unroll
    for (int half = 0; half < 2; half++) {
      int sl = (wid + half * 4) * 8;
#pragma unroll
      for (int j = 0; j < 8; j++)
        vld[half * 8 + j] = Vrow[(size_t)(sl + j) * C + vd];
    }
  };
  auto write_V = [&](int buf) {
#pragma unroll
    for (int half = 0; half < 2; half++) {
      int4 pk;
      pk.x = (unsigned)vld[half * 8 + 0] | ((unsigned)vld[half * 8 + 1] << 16);
      pk.y = (unsigned)vld[half * 8 + 2] | ((unsigned)vld[half * 8 + 3] << 16);
      pk.z = (unsigned)vld[half * 8 + 4] | ((unsigned)vld[half * 8 + 5] << 16);
      pk.w = (unsigned)vld[half * 8 + 6] | ((unsigned)vld[half * 8 + 7] << 16);
      *(int4*)&Vt[buf][vd][(((wid + half * 4) ^ vd) & 7) * 8] = pk;
    }
  };

  load_K(0, 0);
  load_V(0);
  write_V(0);
  __syncthreads();

  for (int ti = 0; ti < ntiles; ti++) {
    const int cur = ti & 1;
    const bool more = (ti + 1 < ntiles);
    const int s0 = s0_of(ti);
    if (more) { load_K(ti + 1, cur ^ 1); load_V(ti + 1); }

    // ---- S = Q K^T ----
    f32x4 sa[4];
#pragma unroll
    for (int nt = 0; nt < 4; nt++) sa[nt] = (f32x4){0.f, 0.f, 0.f, 0.f};
#pragma unroll
    for (int ks = 0; ks < 2; ks++)
#pragma unroll
      for (int nt = 0; nt < 4; nt++) {
        s16x8 kb2 = *(const s16x8*)&Ks[cur][nt * 16 + lr][(((ks * 4 + lg) ^ lr) & 7) * 8];
        sa[nt] = __builtin_amdgcn_mfma_f32_16x16x32_bf16(
            asbf(qf[ks]), asbf(kb2), sa[nt], 0, 0, 0);
      }

    if (ti == self_tiles - 1 && s0 < T) {
#pragma unroll
      for (int nt = 0; nt < 4; nt++)
#pragma unroll
        for (int r = 0; r < 4; r++) {
          int qg = q0 + wid * 16 + lg * 4 + r;
          int sg = s0 + nt * 16 + lr;
          if (sg > qg) sa[nt][r] = -1e30f;
        }
    }

    // ---- online softmax, defer-max + per-lane partial sum ----
    float lm[4];
    bool ok = true;
#pragma unroll
    for (int r = 0; r < 4; r++) {
      lm[r] = fmaxf(fmaxf(sa[0][r], sa[1][r]), fmaxf(sa[2][r], sa[3][r]));
      ok = ok && (lm[r] <= m[r] + 8.f);
    }
    if (!__all(ok)) {
#pragma unroll
      for (int r = 0; r < 4; r++) {
        float tm = lm[r];
#pragma unroll
        for (int msk = 1; msk < 16; msk <<= 1) tm = fmaxf(tm, __shfl_xor(tm, msk, 64));
        float mn = fmaxf(m[r], tm);
        float alpha = __builtin_amdgcn_exp2f(m[r] - mn);
        m[r] = mn;
        lsum[r] *= alpha;
#pragma unroll
        for (int d = 0; d < 4; d++) o[d][r] *= alpha;
      }
    }
    float p[4][4];
#pragma unroll
    for (int r = 0; r < 4; r++) {
      float rs = 0.f;
#pragma unroll
      for (int nt = 0; nt < 4; nt++) {
        float pv = __builtin_amdgcn_exp2f(sa[nt][r] - m[r]);
        p[nt][r] = pv; rs += pv;
      }
      lsum[r] += rs;   // per-lane partial; reduced at epilogue
    }

    // ---- P -> LDS (swizzled), O += P @ V ----
#pragma unroll
    for (int nt = 0; nt < 4; nt++)
#pragma unroll
      for (int r = 0; r < 4; r++) {
        int row = lg * 4 + r, col = nt * 16 + lr;
        Ps[wid][row][(((col >> 3) ^ row) & 7) * 8 + (col & 7)] = (short)f2bf(p[nt][r]);
      }

#pragma unroll
    for (int ks = 0; ks < 2; ks++) {
      s16x8 pa = *(const s16x8*)&Ps[wid][lr][(((ks * 4 + lg) ^ lr) & 7) * 8];
#pragma unroll
      for (int dt = 0; dt < 4; dt++) {
        s16x8 vb2 = *(const s16x8*)&Vt[cur][dt * 16 + lr][(((ks * 4 + lg) ^ lr) & 7) * 8];
        o[dt] = __builtin_amdgcn_mfma_f32_16x16x32_bf16(
            asbf(pa), asbf(vb2), o[dt], 0, 0, 0);
      }
    }

    if (more) write_V(cur ^ 1);
    __syncthreads();
  }

  // epilogue: reduce per-lane partial sums, write swizzled Y
#pragma unroll
  for (int r = 0; r < 4; r++) {
    float s = lsum[r];
#pragma unroll
    for (int msk = 1; msk < 16; msk <<= 1) s += __shfl_xor(s, msk, 64);
    float inv = 1.0f / s;
    int qrow = b * T + q0 + wid * 16 + lg * 4 + r;
#pragma unroll
    for (int dt = 0; dt < 4; dt++) {
      int col = hc + dt * 16 + lr;
      int cb = col >> 3;
      int cs = (cb & ~7) | ((cb ^ qrow) & 7);
      Y[(size_t)qrow * C + cs * 8 + (col & 7)] = f2bf(o[dt][r] * inv);
    }
  }
}

// ---------------------------------------------------------------------------
extern "C" void kernel_launch(void* const* d_in, const int* in_sizes, int n_in,
                              void* d_out, int out_size, void* d_ws, size_t ws_size,
                              hipStream_t stream) {
  const float* x   = (const float*)d_in[0];
  const float* ref = (const float*)d_in[1];
  const float* Wq  = (const float*)d_in[2];
  const float* bq  = (const float*)d_in[3];
  const float* Wk  = (const float*)d_in[4];
  const float* bk  = (const float*)d_in[5];
  const float* Wv  = (const float*)d_in[6];
  const float* bv  = (const float*)d_in[7];
  const float* Wrk = (const float*)d_in[8];
  const float* brk = (const float*)d_in[9];
  const float* Wrv = (const float*)d_in[10];
  const float* brv = (const float*)d_in[11];
  const float* Wp  = (const float*)d_in[12];
  const float* bp  = (const float*)d_in[13];
  float* out = (float*)d_out;

  char* ws = (char*)d_ws;
  auto alloc = [&](size_t bytes) {
    char* p = ws; ws += (bytes + 255) & ~(size_t)255; return p;
  };
  const size_t WB = (size_t)1024 * 1024 * 2;
  unsigned short* Wqkv = (unsigned short*)alloc(3 * WB);  // [3072][1024]
  unsigned short* Wrkv = (unsigned short*)alloc(2 * WB);  // [2048][1024]
  unsigned short* WpT  = (unsigned short*)alloc(WB);
  unsigned short* xg = (unsigned short*)alloc((size_t)8192 * 1024 * 2);
  unsigned short* rg = (unsigned short*)alloc((size_t)2048 * 1024 * 2);
  unsigned short* qb = (unsigned short*)alloc((size_t)8192 * 1024 * 2);
  unsigned short* kb = (unsigned short*)alloc((size_t)4 * 2560 * 1024 * 2);
  unsigned short* vb = (unsigned short*)alloc((size_t)4 * 2560 * 1024 * 2);
  unsigned short* yb = (unsigned short*)alloc((size_t)8192 * 1024 * 2);

  dim3 tb(256);
  dim3 tg(16, 16);
  wtrans<<<tg, tb, 0, stream>>>(Wq,  Wqkv);
  wtrans<<<tg, tb, 0, stream>>>(Wk,  Wqkv + (size_t)1024 * 1024);
  wtrans<<<tg, tb, 0, stream>>>(Wv,  Wqkv + (size_t)2048 * 1024);
  wtrans<<<tg, tb, 0, stream>>>(Wrk, Wrkv);
  wtrans<<<tg, tb, 0, stream>>>(Wrv, Wrkv + (size_t)1024 * 1024);
  wtrans<<<tg, tb, 0, stream>>>(Wp,  WpT);

  convswz<<<dim3(4096), tb, 0, stream>>>(x, xg);
  convswz<<<dim3(1024), tb, 0, stream>>>(ref, rg);

  gemm_bt<0><<<dim3(24, 64), tb, 0, stream>>>(xg, Wqkv, bq, bk, bv, qb, kb, vb);
  gemm_bt<1><<<dim3(16, 16), tb, 0, stream>>>(rg, Wrkv, brk, brv, nullptr, kb, vb, nullptr);

  attn<<<dim3(32, 64), tb, 0, stream>>>(qb, kb, vb, yb);

  gemm_bt<2><<<dim3(8, 64), tb, 0, stream>>>(yb, WpT, bp, bp, bp, out, out, out);
}

// Round 4
// 316.233 us; speedup vs baseline: 1.9741x; 1.0169x over previous
//
#include <hip/hip_runtime.h>
#include <hip/hip_bf16.h>

typedef short s16x4 __attribute__((ext_vector_type(4)));
typedef short s16x8 __attribute__((ext_vector_type(8)));
typedef __bf16 bf16x8 __attribute__((ext_vector_type(8)));
typedef float f32x4 __attribute__((ext_vector_type(4)));

#define DEVI static __device__ __forceinline__

DEVI unsigned short f2bf(float x) {
  union { float f; unsigned u; } a; a.f = x;
  unsigned r = a.u + 0x7fffu + ((a.u >> 16) & 1u);
  return (unsigned short)(r >> 16);
}
DEVI float bf2f(unsigned short s) {
  union { unsigned u; float f; } a; a.u = ((unsigned)s) << 16; return a.f;
}
DEVI bf16x8 asbf(s16x8 v) {
  union { s16x8 s; bf16x8 b; } u; u.s = v; return u.b;
}
DEVI unsigned cvtpk(float lo, float hi) {
  unsigned r;
  asm("v_cvt_pk_bf16_f32 %0, %1, %2" : "=v"(r) : "v"(lo), "v"(hi));
  return r;
}
DEVI void gload16(const void* g, void* l) {
  __builtin_amdgcn_global_load_lds(
      (const __attribute__((address_space(1))) void*)g,
      (__attribute__((address_space(3))) void*)l, 16, 0, 0);
}

// ---------------------------------------------------------------------------
// Weight transpose + fp32->bf16, PRE-SWIZZLED for linear global_load_lds.
// ---------------------------------------------------------------------------
__global__ __launch_bounds__(256)
void wtrans(const float* __restrict__ W, unsigned short* __restrict__ WT) {
  __shared__ short tile[64][65];
  const int n0 = blockIdx.x * 64;
  const int k0 = blockIdx.y * 64;
  const int t = threadIdx.x;
#pragma unroll
  for (int i = 0; i < 4; i++) {
    int f = t + i * 256;
    int r = f >> 4, c = (f & 15) * 4;
    float4 v = *(const float4*)(W + (size_t)(k0 + r) * 1024 + n0 + c);
    tile[r][c + 0] = (short)f2bf(v.x);
    tile[r][c + 1] = (short)f2bf(v.y);
    tile[r][c + 2] = (short)f2bf(v.z);
    tile[r][c + 3] = (short)f2bf(v.w);
  }
  __syncthreads();
#pragma unroll
  for (int i = 0; i < 2; i++) {
    int f = t + i * 256;
    int r = f >> 3, c8 = f & 7;
    s16x8 o;
#pragma unroll
    for (int j = 0; j < 8; j++) o[j] = tile[c8 * 8 + j][r];
    *(s16x8*)(WT + (size_t)(n0 + r) * 1024 + k0 + ((c8 ^ (r & 7)) & 7) * 8) = o;
  }
}

// ---------------------------------------------------------------------------
// fp32 -> bf16 convert, pre-swizzled by row (within 64-col K-tiles).
// ---------------------------------------------------------------------------
__global__ __launch_bounds__(256)
void convswz(const float* __restrict__ X, unsigned short* __restrict__ Xg) {
  int f = blockIdx.x * 256 + threadIdx.x;
  int row = f >> 7, c8 = f & 127;
  const float* src = X + (size_t)row * 1024 + c8 * 8;
  float4 a = *(const float4*)src;
  float4 b2 = *(const float4*)(src + 4);
  s16x8 o;
  o[0] = (short)f2bf(a.x);  o[1] = (short)f2bf(a.y);
  o[2] = (short)f2bf(a.z);  o[3] = (short)f2bf(a.w);
  o[4] = (short)f2bf(b2.x); o[5] = (short)f2bf(b2.y);
  o[6] = (short)f2bf(b2.z); o[7] = (short)f2bf(b2.w);
  int cs = (c8 & ~7) | ((c8 ^ row) & 7);
  *(s16x8*)(Xg + (size_t)row * 1024 + cs * 8) = o;
}

// ---------------------------------------------------------------------------
// GEMM: A (bf16, pre-swizzled) @ BT (bf16, pre-swizzled) + bias.
// 128x128 tile, BK=64, 4 waves; global_load_lds width-16 staging.
// MODE 0: QKV fused (N=3072) -> qb | kb(swz) | vbT(transposed).
// MODE 1: refKV fused (N=2048) -> kb(swz) | vbT at s>=2048.
// MODE 2: proj (N=1024) -> fp32 out.
// ---------------------------------------------------------------------------
template<int MODE>
__global__ __launch_bounds__(256)
void gemm_bt(const unsigned short* __restrict__ A, const unsigned short* __restrict__ BT,
             const float* __restrict__ b0, const float* __restrict__ b1,
             const float* __restrict__ b2,
             void* __restrict__ o0, void* __restrict__ o1, void* __restrict__ o2)
{
  const int K = 1024;
  __shared__ __align__(16) short As[128][64];
  __shared__ __align__(16) short Bs[128][64];
  const int t = threadIdx.x;
  const int lane = t & 63, wid = t >> 6;
  const int wm = wid >> 1, wn = wid & 1;
  const int lr = lane & 15, lg = lane >> 4;
  const size_t m0 = (size_t)blockIdx.y * 128;
  const int n0 = blockIdx.x * 128;

  f32x4 acc[4][4];
#pragma unroll
  for (int i = 0; i < 4; i++)
#pragma unroll
    for (int j = 0; j < 4; j++) acc[i][j] = (f32x4){0.f, 0.f, 0.f, 0.f};

  const unsigned short* Abase = A + m0 * K;
  const unsigned short* Bbase = BT + (size_t)n0 * K;
  const int r_ld = t >> 3, cb_ld = t & 7;

  for (int k0 = 0; k0 < K; k0 += 64) {
#pragma unroll
    for (int i = 0; i < 4; i++) {
      int r = r_ld + i * 32;
      gload16(Abase + (size_t)r * K + k0 + cb_ld * 8,
              (short*)As + (i * 256 + wid * 64) * 8);
      gload16(Bbase + (size_t)r * K + k0 + cb_ld * 8,
              (short*)Bs + (i * 256 + wid * 64) * 8);
    }
    __syncthreads();
#pragma unroll
    for (int ks = 0; ks < 2; ks++) {
      s16x8 af[4], bfr[4];
#pragma unroll
      for (int i = 0; i < 4; i++)
        af[i] = *(const s16x8*)&As[wm * 64 + i * 16 + lr][(((ks * 4 + lg) ^ lr) & 7) * 8];
#pragma unroll
      for (int i = 0; i < 4; i++)
        bfr[i] = *(const s16x8*)&Bs[wn * 64 + i * 16 + lr][(((ks * 4 + lg) ^ lr) & 7) * 8];
#pragma unroll
      for (int mi = 0; mi < 4; mi++)
#pragma unroll
        for (int ni = 0; ni < 4; ni++)
          acc[mi][ni] = __builtin_amdgcn_mfma_f32_16x16x32_bf16(
              asbf(af[mi]), asbf(bfr[ni]), acc[mi][ni], 0, 0, 0);
    }
    __syncthreads();
  }

  const int seg = n0 >> 10;
  const float* bb = (seg == 0) ? b0 : (seg == 1 ? b1 : b2);
#pragma unroll
  for (int mi = 0; mi < 4; mi++) {
#pragma unroll
    for (int ni = 0; ni < 4; ni++) {
      int cg = n0 + wn * 64 + ni * 16 + lr;
      int c = cg & 1023;
      float bv = bb[c];
      const bool vseg = (MODE == 0 && seg == 2) || (MODE == 1 && seg == 1);
      if (MODE != 2 && vseg) {
        // transposed V: vbT[(b*16+h)*64 + d][2560], pre-swizzled per 64-s tile
        int rm0 = (int)m0 + wm * 64 + mi * 16 + lg * 4;
        int d = c & 63, hh = c >> 6;
        int bb_, s;
        if (MODE == 0) { bb_ = rm0 >> 11; s = rm0 & 2047; }
        else           { bb_ = rm0 >> 9;  s = 2048 + (rm0 & 511); }
        int scol = (s & ~63) + ((((s >> 3) ^ d) & 7) << 3) + (s & 7);
        unsigned short* dst = (unsigned short*)(MODE == 0 ? o2 : o1);
        short4 pk4;
        pk4.x = (short)f2bf(acc[mi][ni][0] + bv);
        pk4.y = (short)f2bf(acc[mi][ni][1] + bv);
        pk4.z = (short)f2bf(acc[mi][ni][2] + bv);
        pk4.w = (short)f2bf(acc[mi][ni][3] + bv);
        *(short4*)(dst + ((size_t)(bb_ * 16 + hh) * 64 + d) * 2560 + scol) = pk4;
      } else {
#pragma unroll
        for (int r = 0; r < 4; r++) {
          int rm = (int)m0 + wm * 64 + mi * 16 + lg * 4 + r;
          float val = acc[mi][ni][r] + bv;
          if (MODE == 2) {
            ((float*)o0)[(size_t)rm * 1024 + cg] = val;
          } else {
            size_t orow; unsigned short* dst; bool swz;
            if (MODE == 0) {
              if (seg == 0) { dst = (unsigned short*)o0; orow = rm; swz = false; }
              else { orow = (size_t)(rm >> 11) * 2560 + (rm & 2047);
                     dst = (unsigned short*)o1; swz = true; }
            } else {
              orow = (size_t)(rm >> 9) * 2560 + 2048 + (rm & 511);
              dst = (unsigned short*)o0; swz = true;
            }
            int cc = c;
            if (swz) cc = (c & ~63) | ((((c >> 3) ^ (int)orow) & 7) << 3) | (c & 7);
            dst[orow * 1024 + cc] = f2bf(val);
          }
        }
      }
    }
  }
}

// ---------------------------------------------------------------------------
// Flash attention v4: swapped QK^T (lane-local q-rows), in-register P
// exchange (cvt_pk + shfl), gload_lds staging for BOTH K and transposed V.
// ---------------------------------------------------------------------------
__global__ __launch_bounds__(256, 4)
void attn(const unsigned short* __restrict__ Q, const unsigned short* __restrict__ Kb,
          const unsigned short* __restrict__ VbT, unsigned short* __restrict__ Y)
{
  const int T = 2048, S = 2560, C = 1024, TREF = 512;
  __shared__ __align__(16) short Ks[2][64][64];
  __shared__ __align__(16) short Vt[2][64][64];   // Vt[d][s]
  const int t = threadIdx.x;
  const int lane = t & 63, wid = t >> 6;
  const int lr = lane & 15, lg = lane >> 4;
  const int q0 = blockIdx.x * 64;
  const int bh = blockIdx.y;
  const int b = bh >> 4;
  const int hc = (bh & 15) * 64;

  // Q fragments (B-operand now; same lane layout), scaled by (1/8)*log2(e)
  const float QSC = 0.125f * 1.44269504088896f;
  s16x8 qf[2];
  {
    size_t qrow = (size_t)(b * T + q0 + wid * 16 + lr);
#pragma unroll
    for (int ks = 0; ks < 2; ks++) {
      s16x8 v = *(const s16x8*)(Q + qrow * C + hc + ks * 32 + lg * 8);
#pragma unroll
      for (int j = 0; j < 8; j++)
        v[j] = (short)f2bf(bf2f((unsigned short)v[j]) * QSC);
      qf[ks] = v;
    }
  }

  float mrow = -1e30f, lsum = 0.f;
  f32x4 o[4];
#pragma unroll
  for (int d = 0; d < 4; d++) o[d] = (f32x4){0.f, 0.f, 0.f, 0.f};

  const int self_tiles = blockIdx.x + 1;
  const int ntiles = self_tiles + TREF / 64;

  auto s0_of = [&](int ti2) {
    return (ti2 < self_tiles) ? ti2 * 64 : T + (ti2 - self_tiles) * 64;
  };
  const int r_ld = t >> 3, cb_ld = t & 7;
  auto load_K = [&](int ti2, int buf) {
    int s0 = s0_of(ti2);
    const unsigned short* Krow = Kb + (size_t)(b * S + s0) * C + hc;
#pragma unroll
    for (int i = 0; i < 2; i++)
      gload16(Krow + (size_t)(r_ld + i * 32) * C + cb_ld * 8,
              (short*)&Ks[buf][0][0] + (i * 256 + wid * 64) * 8);
  };
  auto load_V = [&](int ti2, int buf) {
    int s0 = s0_of(ti2);
    const unsigned short* Vr = VbT + (size_t)bh * 64 * S + s0;
#pragma unroll
    for (int i = 0; i < 2; i++)
      gload16(Vr + (size_t)(r_ld + i * 32) * S + cb_ld * 8,
              (short*)&Vt[buf][0][0] + (i * 256 + wid * 64) * 8);
  };

  load_K(0, 0);
  load_V(0, 0);
  __syncthreads();

  for (int ti = 0; ti < ntiles; ti++) {
    const int cur = ti & 1;
    const bool more = (ti + 1 < ntiles);
    if (more) { load_K(ti + 1, cur ^ 1); load_V(ti + 1, cur ^ 1); }

    // ---- S^T = K Q^T : D[s][q], q = lane&15, s = nt*16 + lg*4 + reg ----
    f32x4 sa[4];
#pragma unroll
    for (int nt = 0; nt < 4; nt++) sa[nt] = (f32x4){0.f, 0.f, 0.f, 0.f};
#pragma unroll
    for (int ks = 0; ks < 2; ks++)
#pragma unroll
      for (int nt = 0; nt < 4; nt++) {
        s16x8 kb2 = *(const s16x8*)&Ks[cur][nt * 16 + lr][(((ks * 4 + lg) ^ lr) & 7) * 8];
        sa[nt] = __builtin_amdgcn_mfma_f32_16x16x32_bf16(
            asbf(kb2), asbf(qf[ks]), sa[nt], 0, 0, 0);
      }

    if (ti == self_tiles - 1) {   // diagonal self tile: s0 == q0
      int qg = wid * 16 + lr;
#pragma unroll
      for (int nt = 0; nt < 4; nt++)
#pragma unroll
        for (int r = 0; r < 4; r++)
          if (nt * 16 + lg * 4 + r > qg) sa[nt][r] = -1e30f;
    }

    // ---- online softmax: lane owns q = lr; defer-max ----
    float lm = sa[0][0];
#pragma unroll
    for (int nt = 0; nt < 4; nt++)
#pragma unroll
      for (int r = 0; r < 4; r++) lm = fmaxf(lm, sa[nt][r]);
    if (!__all(lm <= mrow + 8.f)) {
      float tm = lm;
      tm = fmaxf(tm, __shfl_xor(tm, 16, 64));
      tm = fmaxf(tm, __shfl_xor(tm, 32, 64));
      float mn = fmaxf(mrow, tm);
      float alpha = __builtin_amdgcn_exp2f(mrow - mn);
      mrow = mn;
      lsum *= alpha;
#pragma unroll
      for (int r = 0; r < 4; r++) {
        float ar = __shfl(alpha, lg * 4 + r, 64);
#pragma unroll
        for (int dt = 0; dt < 4; dt++) o[dt][r] *= ar;
      }
    }

    unsigned pk2[4][2];
    float rs = 0.f;
#pragma unroll
    for (int nt = 0; nt < 4; nt++) {
      float p0 = __builtin_amdgcn_exp2f(sa[nt][0] - mrow);
      float p1 = __builtin_amdgcn_exp2f(sa[nt][1] - mrow);
      float p2 = __builtin_amdgcn_exp2f(sa[nt][2] - mrow);
      float p3 = __builtin_amdgcn_exp2f(sa[nt][3] - mrow);
      rs += (p0 + p1) + (p2 + p3);
      pk2[nt][0] = cvtpk(p0, p1);
      pk2[nt][1] = cvtpk(p2, p3);
    }
    lsum += rs;

    // ---- in-register exchange: build PA fragments (row=q=lr, k=s) ----
    s16x8 pa[2];
#pragma unroll
    for (int ks = 0; ks < 2; ks++) {
      union { unsigned w[4]; s16x8 v; } U;
#pragma unroll
      for (int w = 0; w < 4; w++) {
        int srcL = lr + (((lg & 1) * 2 + (w >> 1)) << 4);
        unsigned v0 = __shfl((int)pk2[2 * ks][w & 1], srcL, 64);
        unsigned v1 = __shfl((int)pk2[2 * ks + 1][w & 1], srcL, 64);
        U.w[w] = (lg & 2) ? v1 : v0;
      }
      pa[ks] = U.v;
    }

    // ---- O += P @ V ----
#pragma unroll
    for (int ks = 0; ks < 2; ks++)
#pragma unroll
      for (int dt = 0; dt < 4; dt++) {
        s16x8 vb2 = *(const s16x8*)&Vt[cur][dt * 16 + lr][(((ks * 4 + lg) ^ lr) & 7) * 8];
        o[dt] = __builtin_amdgcn_mfma_f32_16x16x32_bf16(
            asbf(pa[ks]), asbf(vb2), o[dt], 0, 0, 0);
      }

    __syncthreads();
  }

  // epilogue: reduce lsum over the 4 lanes sharing each q, divide, write Y
  float tot = lsum;
  tot += __shfl_xor(tot, 16, 64);
  tot += __shfl_xor(tot, 32, 64);
#pragma unroll
  for (int r = 0; r < 4; r++) {
    float inv = 1.0f / __shfl(tot, lg * 4 + r, 64);
    int qrow = b * T + q0 + wid * 16 + lg * 4 + r;
#pragma unroll
    for (int dt = 0; dt < 4; dt++) {
      int col = hc + dt * 16 + lr;
      int cb = col >> 3;
      int cs = (cb & ~7) | ((cb ^ qrow) & 7);
      Y[(size_t)qrow * C + cs * 8 + (col & 7)] = f2bf(o[dt][r] * inv);
    }
  }
}

// ---------------------------------------------------------------------------
extern "C" void kernel_launch(void* const* d_in, const int* in_sizes, int n_in,
                              void* d_out, int out_size, void* d_ws, size_t ws_size,
                              hipStream_t stream) {
  const float* x   = (const float*)d_in[0];
  const float* ref = (const float*)d_in[1];
  const float* Wq  = (const float*)d_in[2];
  const float* bq  = (const float*)d_in[3];
  const float* Wk  = (const float*)d_in[4];
  const float* bk  = (const float*)d_in[5];
  const float* Wv  = (const float*)d_in[6];
  const float* bv  = (const float*)d_in[7];
  const float* Wrk = (const float*)d_in[8];
  const float* brk = (const float*)d_in[9];
  const float* Wrv = (const float*)d_in[10];
  const float* brv = (const float*)d_in[11];
  const float* Wp  = (const float*)d_in[12];
  const float* bp  = (const float*)d_in[13];
  float* out = (float*)d_out;

  char* ws = (char*)d_ws;
  auto alloc = [&](size_t bytes) {
    char* p = ws; ws += (bytes + 255) & ~(size_t)255; return p;
  };
  const size_t WB = (size_t)1024 * 1024 * 2;
  unsigned short* Wqkv = (unsigned short*)alloc(3 * WB);
  unsigned short* Wrkv = (unsigned short*)alloc(2 * WB);
  unsigned short* WpT  = (unsigned short*)alloc(WB);
  unsigned short* xg  = (unsigned short*)alloc((size_t)8192 * 1024 * 2);
  unsigned short* rg  = (unsigned short*)alloc((size_t)2048 * 1024 * 2);
  unsigned short* qb  = (unsigned short*)alloc((size_t)8192 * 1024 * 2);
  unsigned short* kb  = (unsigned short*)alloc((size_t)4 * 2560 * 1024 * 2);
  unsigned short* vbT = (unsigned short*)alloc((size_t)4096 * 2560 * 2);
  unsigned short* yb  = (unsigned short*)alloc((size_t)8192 * 1024 * 2);

  dim3 tb(256);
  dim3 tg(16, 16);
  wtrans<<<tg, tb, 0, stream>>>(Wq,  Wqkv);
  wtrans<<<tg, tb, 0, stream>>>(Wk,  Wqkv + (size_t)1024 * 1024);
  wtrans<<<tg, tb, 0, stream>>>(Wv,  Wqkv + (size_t)2048 * 1024);
  wtrans<<<tg, tb, 0, stream>>>(Wrk, Wrkv);
  wtrans<<<tg, tb, 0, stream>>>(Wrv, Wrkv + (size_t)1024 * 1024);
  wtrans<<<tg, tb, 0, stream>>>(Wp,  WpT);

  convswz<<<dim3(4096), tb, 0, stream>>>(x, xg);
  convswz<<<dim3(1024), tb, 0, stream>>>(ref, rg);

  gemm_bt<0><<<dim3(24, 64), tb, 0, stream>>>(xg, Wqkv, bq, bk, bv, qb, kb, vbT);
  gemm_bt<1><<<dim3(16, 16), tb, 0, stream>>>(rg, Wrkv, brk, brv, nullptr, kb, vbT, nullptr);

  attn<<<dim3(32, 64), tb, 0, stream>>>(qb, kb, vbT, yb);

  gemm_bt<2><<<dim3(8, 64), tb, 0, stream>>>(yb, WpT, bp, bp, bp, out, out, out);
}

// Round 5
// 295.776 us; speedup vs baseline: 2.1106x; 1.0692x over previous
//
#include <hip/hip_runtime.h>
#include <hip/hip_bf16.h>

typedef short s16x4 __attribute__((ext_vector_type(4)));
typedef short s16x8 __attribute__((ext_vector_type(8)));
typedef __bf16 bf16x8 __attribute__((ext_vector_type(8)));
typedef float f32x4 __attribute__((ext_vector_type(4)));

#define DEVI static __device__ __forceinline__

DEVI unsigned short f2bf(float x) {
  union { float f; unsigned u; } a; a.f = x;
  unsigned r = a.u + 0x7fffu + ((a.u >> 16) & 1u);
  return (unsigned short)(r >> 16);
}
DEVI float bf2f(unsigned short s) {
  union { unsigned u; float f; } a; a.u = ((unsigned)s) << 16; return a.f;
}
DEVI bf16x8 asbf(s16x8 v) {
  union { s16x8 s; bf16x8 b; } u; u.s = v; return u.b;
}
DEVI unsigned cvtpk(float lo, float hi) {
  unsigned r;
  asm("v_cvt_pk_bf16_f32 %0, %1, %2" : "=v"(r) : "v"(lo), "v"(hi));
  return r;
}
DEVI void gload16(const void* g, void* l) {
  __builtin_amdgcn_global_load_lds(
      (const __attribute__((address_space(1))) void*)g,
      (__attribute__((address_space(3))) void*)l, 16, 0, 0);
}

// ---------------------------------------------------------------------------
// Weight transpose + fp32->bf16, PRE-SWIZZLED for linear global_load_lds.
// ---------------------------------------------------------------------------
__global__ __launch_bounds__(256)
void wtrans(const float* __restrict__ W, unsigned short* __restrict__ WT) {
  __shared__ short tile[64][65];
  const int n0 = blockIdx.x * 64;
  const int k0 = blockIdx.y * 64;
  const int t = threadIdx.x;
#pragma unroll
  for (int i = 0; i < 4; i++) {
    int f = t + i * 256;
    int r = f >> 4, c = (f & 15) * 4;
    float4 v = *(const float4*)(W + (size_t)(k0 + r) * 1024 + n0 + c);
    tile[r][c + 0] = (short)f2bf(v.x);
    tile[r][c + 1] = (short)f2bf(v.y);
    tile[r][c + 2] = (short)f2bf(v.z);
    tile[r][c + 3] = (short)f2bf(v.w);
  }
  __syncthreads();
#pragma unroll
  for (int i = 0; i < 2; i++) {
    int f = t + i * 256;
    int r = f >> 3, c8 = f & 7;
    s16x8 o;
#pragma unroll
    for (int j = 0; j < 8; j++) o[j] = tile[c8 * 8 + j][r];
    *(s16x8*)(WT + (size_t)(n0 + r) * 1024 + k0 + ((c8 ^ (r & 7)) & 7) * 8) = o;
  }
}

// ---------------------------------------------------------------------------
// fp32 -> bf16 convert, pre-swizzled by row (within 64-col K-tiles).
// ---------------------------------------------------------------------------
__global__ __launch_bounds__(256)
void convswz(const float* __restrict__ X, unsigned short* __restrict__ Xg) {
  int f = blockIdx.x * 256 + threadIdx.x;
  int row = f >> 7, c8 = f & 127;
  const float* src = X + (size_t)row * 1024 + c8 * 8;
  float4 a = *(const float4*)src;
  float4 b2 = *(const float4*)(src + 4);
  s16x8 o;
  o[0] = (short)f2bf(a.x);  o[1] = (short)f2bf(a.y);
  o[2] = (short)f2bf(a.z);  o[3] = (short)f2bf(a.w);
  o[4] = (short)f2bf(b2.x); o[5] = (short)f2bf(b2.y);
  o[6] = (short)f2bf(b2.z); o[7] = (short)f2bf(b2.w);
  int cs = (c8 & ~7) | ((c8 ^ row) & 7);
  *(s16x8*)(Xg + (size_t)row * 1024 + cs * 8) = o;
}

// ---------------------------------------------------------------------------
// GEMM: A (bf16, pre-swizzled) @ BT (bf16, pre-swizzled) + bias.
// 128x128 tile, BK=64, 4 waves; global_load_lds width-16 staging.
// MODE 0: QKV fused (N=3072) -> qb | kb(swz) | vbT(transposed).
// MODE 1: refKV fused (N=2048) -> kb(swz) | vbT at s>=2048.
// MODE 2: proj (N=1024) -> fp32 out.
// ---------------------------------------------------------------------------
template<int MODE>
__global__ __launch_bounds__(256)
void gemm_bt(const unsigned short* __restrict__ A, const unsigned short* __restrict__ BT,
             const float* __restrict__ b0, const float* __restrict__ b1,
             const float* __restrict__ b2,
             void* __restrict__ o0, void* __restrict__ o1, void* __restrict__ o2)
{
  const int K = 1024;
  __shared__ __align__(16) short As[128][64];
  __shared__ __align__(16) short Bs[128][64];
  const int t = threadIdx.x;
  const int lane = t & 63, wid = t >> 6;
  const int wm = wid >> 1, wn = wid & 1;
  const int lr = lane & 15, lg = lane >> 4;
  const size_t m0 = (size_t)blockIdx.y * 128;
  const int n0 = blockIdx.x * 128;

  f32x4 acc[4][4];
#pragma unroll
  for (int i = 0; i < 4; i++)
#pragma unroll
    for (int j = 0; j < 4; j++) acc[i][j] = (f32x4){0.f, 0.f, 0.f, 0.f};

  const unsigned short* Abase = A + m0 * K;
  const unsigned short* Bbase = BT + (size_t)n0 * K;
  const int r_ld = t >> 3, cb_ld = t & 7;

  for (int k0 = 0; k0 < K; k0 += 64) {
#pragma unroll
    for (int i = 0; i < 4; i++) {
      int r = r_ld + i * 32;
      gload16(Abase + (size_t)r * K + k0 + cb_ld * 8,
              (short*)As + (i * 256 + wid * 64) * 8);
      gload16(Bbase + (size_t)r * K + k0 + cb_ld * 8,
              (short*)Bs + (i * 256 + wid * 64) * 8);
    }
    __syncthreads();
#pragma unroll
    for (int ks = 0; ks < 2; ks++) {
      s16x8 af[4], bfr[4];
#pragma unroll
      for (int i = 0; i < 4; i++)
        af[i] = *(const s16x8*)&As[wm * 64 + i * 16 + lr][(((ks * 4 + lg) ^ lr) & 7) * 8];
#pragma unroll
      for (int i = 0; i < 4; i++)
        bfr[i] = *(const s16x8*)&Bs[wn * 64 + i * 16 + lr][(((ks * 4 + lg) ^ lr) & 7) * 8];
#pragma unroll
      for (int mi = 0; mi < 4; mi++)
#pragma unroll
        for (int ni = 0; ni < 4; ni++)
          acc[mi][ni] = __builtin_amdgcn_mfma_f32_16x16x32_bf16(
              asbf(af[mi]), asbf(bfr[ni]), acc[mi][ni], 0, 0, 0);
    }
    __syncthreads();
  }

  const int seg = n0 >> 10;
  const float* bb = (seg == 0) ? b0 : (seg == 1 ? b1 : b2);
#pragma unroll
  for (int mi = 0; mi < 4; mi++) {
#pragma unroll
    for (int ni = 0; ni < 4; ni++) {
      int cg = n0 + wn * 64 + ni * 16 + lr;
      int c = cg & 1023;
      float bv = bb[c];
      const bool vseg = (MODE == 0 && seg == 2) || (MODE == 1 && seg == 1);
      if (MODE != 2 && vseg) {
        // transposed V: vbT[(b*16+h)*64 + d][2560], pre-swizzled per 64-s tile
        int rm0 = (int)m0 + wm * 64 + mi * 16 + lg * 4;
        int d = c & 63, hh = c >> 6;
        int bb_, s;
        if (MODE == 0) { bb_ = rm0 >> 11; s = rm0 & 2047; }
        else           { bb_ = rm0 >> 9;  s = 2048 + (rm0 & 511); }
        int scol = (s & ~63) + ((((s >> 3) ^ d) & 7) << 3) + (s & 7);
        unsigned short* dst = (unsigned short*)(MODE == 0 ? o2 : o1);
        short4 pk4;
        pk4.x = (short)f2bf(acc[mi][ni][0] + bv);
        pk4.y = (short)f2bf(acc[mi][ni][1] + bv);
        pk4.z = (short)f2bf(acc[mi][ni][2] + bv);
        pk4.w = (short)f2bf(acc[mi][ni][3] + bv);
        *(short4*)(dst + ((size_t)(bb_ * 16 + hh) * 64 + d) * 2560 + scol) = pk4;
      } else {
#pragma unroll
        for (int r = 0; r < 4; r++) {
          int rm = (int)m0 + wm * 64 + mi * 16 + lg * 4 + r;
          float val = acc[mi][ni][r] + bv;
          if (MODE == 2) {
            ((float*)o0)[(size_t)rm * 1024 + cg] = val;
          } else {
            size_t orow; unsigned short* dst; bool swz;
            if (MODE == 0) {
              if (seg == 0) { dst = (unsigned short*)o0; orow = rm; swz = false; }
              else { orow = (size_t)(rm >> 11) * 2560 + (rm & 2047);
                     dst = (unsigned short*)o1; swz = true; }
            } else {
              orow = (size_t)(rm >> 9) * 2560 + 2048 + (rm & 511);
              dst = (unsigned short*)o0; swz = true;
            }
            int cc = c;
            if (swz) cc = (c & ~63) | ((((c >> 3) ^ (int)orow) & 7) << 3) | (c & 7);
            dst[orow * 1024 + cc] = f2bf(val);
          }
        }
      }
    }
  }
}

// ---------------------------------------------------------------------------
// Flash attention v5: QBLK=128 (2 q-subtiles/block share each K/V tile),
// XCD-aware block remap, swapped QK^T, in-register P exchange.
// ---------------------------------------------------------------------------
__global__ __launch_bounds__(256, 4)
void attn(const unsigned short* __restrict__ Q, const unsigned short* __restrict__ Kb,
          const unsigned short* __restrict__ VbT, unsigned short* __restrict__ Y)
{
  const int T = 2048, S = 2560, C = 1024, TREF = 512;
  __shared__ __align__(16) short Ks[2][64][64];
  __shared__ __align__(16) short Vt[2][64][64];   // Vt[d][s]
  const int t = threadIdx.x;
  const int lane = t & 63, wid = t >> 6;
  const int lr = lane & 15, lg = lane >> 4;

  // XCD-aware remap: 1024 blocks; all 16 q-blocks of a (b,h) on one XCD.
  const int bid = blockIdx.x;
  const int xcd = bid & 7, idx = bid >> 3;
  const int bh = xcd * 8 + (idx >> 4);
  const int bx = idx & 15;
  const int q0 = bx * 128;
  const int b = bh >> 4;
  const int hc = (bh & 15) * 64;

  // Q fragments for both subtiles, scaled by (1/8)*log2(e)
  const float QSC = 0.125f * 1.44269504088896f;
  s16x8 qf[2][2];
#pragma unroll
  for (int j = 0; j < 2; j++) {
    size_t qrow = (size_t)(b * T + q0 + j * 64 + wid * 16 + lr);
#pragma unroll
    for (int ks = 0; ks < 2; ks++) {
      s16x8 v = *(const s16x8*)(Q + qrow * C + hc + ks * 32 + lg * 8);
#pragma unroll
      for (int jj = 0; jj < 8; jj++)
        v[jj] = (short)f2bf(bf2f((unsigned short)v[jj]) * QSC);
      qf[j][ks] = v;
    }
  }

  float mrow[2] = {-1e30f, -1e30f}, lsum[2] = {0.f, 0.f};
  f32x4 o[2][4];
#pragma unroll
  for (int j = 0; j < 2; j++)
#pragma unroll
    for (int d = 0; d < 4; d++) o[j][d] = (f32x4){0.f, 0.f, 0.f, 0.f};

  const int self_tiles = 2 * bx + 2;
  const int ntiles = self_tiles + TREF / 64;

  auto s0_of = [&](int ti2) {
    return (ti2 < self_tiles) ? ti2 * 64 : T + (ti2 - self_tiles) * 64;
  };
  const int r_ld = t >> 3, cb_ld = t & 7;
  auto load_K = [&](int ti2, int buf) {
    int s0 = s0_of(ti2);
    const unsigned short* Krow = Kb + (size_t)(b * S + s0) * C + hc;
#pragma unroll
    for (int i = 0; i < 2; i++)
      gload16(Krow + (size_t)(r_ld + i * 32) * C + cb_ld * 8,
              (short*)&Ks[buf][0][0] + (i * 256 + wid * 64) * 8);
  };
  auto load_V = [&](int ti2, int buf) {
    int s0 = s0_of(ti2);
    const unsigned short* Vr = VbT + (size_t)bh * 64 * S + s0;
#pragma unroll
    for (int i = 0; i < 2; i++)
      gload16(Vr + (size_t)(r_ld + i * 32) * S + cb_ld * 8,
              (short*)&Vt[buf][0][0] + (i * 256 + wid * 64) * 8);
  };

  load_K(0, 0);
  load_V(0, 0);
  __syncthreads();

  for (int ti = 0; ti < ntiles; ti++) {
    const int cur = ti & 1;
    const bool more = (ti + 1 < ntiles);
    if (more) { load_K(ti + 1, cur ^ 1); load_V(ti + 1, cur ^ 1); }

#pragma unroll
    for (int j = 0; j < 2; j++) {
      // subtile j fully masked out at the tile just above its diagonal
      if (j == 0 && ti == 2 * bx + 1) continue;

      // ---- S^T = K Q^T : D[s][q], q = lane&15, s = nt*16 + lg*4 + reg ----
      f32x4 sa[4];
#pragma unroll
      for (int nt = 0; nt < 4; nt++) sa[nt] = (f32x4){0.f, 0.f, 0.f, 0.f};
#pragma unroll
      for (int ks = 0; ks < 2; ks++)
#pragma unroll
        for (int nt = 0; nt < 4; nt++) {
          s16x8 kb2 = *(const s16x8*)&Ks[cur][nt * 16 + lr][(((ks * 4 + lg) ^ lr) & 7) * 8];
          sa[nt] = __builtin_amdgcn_mfma_f32_16x16x32_bf16(
              asbf(kb2), asbf(qf[j][ks]), sa[nt], 0, 0, 0);
        }

      if (ti == 2 * bx + j) {   // diagonal tile for subtile j
        int qg = wid * 16 + lr;
#pragma unroll
        for (int nt = 0; nt < 4; nt++)
#pragma unroll
          for (int r = 0; r < 4; r++)
            if (nt * 16 + lg * 4 + r > qg) sa[nt][r] = -1e30f;
      }

      // ---- online softmax: lane owns q = lr (subtile j); defer-max ----
      float lm = sa[0][0];
#pragma unroll
      for (int nt = 0; nt < 4; nt++)
#pragma unroll
        for (int r = 0; r < 4; r++) lm = fmaxf(lm, sa[nt][r]);
      if (!__all(lm <= mrow[j] + 8.f)) {
        float tm = lm;
        tm = fmaxf(tm, __shfl_xor(tm, 16, 64));
        tm = fmaxf(tm, __shfl_xor(tm, 32, 64));
        float mn = fmaxf(mrow[j], tm);
        float alpha = __builtin_amdgcn_exp2f(mrow[j] - mn);
        mrow[j] = mn;
        lsum[j] *= alpha;
#pragma unroll
        for (int r = 0; r < 4; r++) {
          float ar = __shfl(alpha, lg * 4 + r, 64);
#pragma unroll
          for (int dt = 0; dt < 4; dt++) o[j][dt][r] *= ar;
        }
      }

      unsigned pk2[4][2];
      float rs = 0.f;
#pragma unroll
      for (int nt = 0; nt < 4; nt++) {
        float p0 = __builtin_amdgcn_exp2f(sa[nt][0] - mrow[j]);
        float p1 = __builtin_amdgcn_exp2f(sa[nt][1] - mrow[j]);
        float p2 = __builtin_amdgcn_exp2f(sa[nt][2] - mrow[j]);
        float p3 = __builtin_amdgcn_exp2f(sa[nt][3] - mrow[j]);
        rs += (p0 + p1) + (p2 + p3);
        pk2[nt][0] = cvtpk(p0, p1);
        pk2[nt][1] = cvtpk(p2, p3);
      }
      lsum[j] += rs;

      // ---- in-register exchange: build PA fragments (row=q=lr, k=s) ----
      s16x8 pa[2];
#pragma unroll
      for (int ks = 0; ks < 2; ks++) {
        union { unsigned w[4]; s16x8 v; } U;
#pragma unroll
        for (int w = 0; w < 4; w++) {
          int srcL = lr + (((lg & 1) * 2 + (w >> 1)) << 4);
          unsigned v0 = __shfl((int)pk2[2 * ks][w & 1], srcL, 64);
          unsigned v1 = __shfl((int)pk2[2 * ks + 1][w & 1], srcL, 64);
          U.w[w] = (lg & 2) ? v1 : v0;
        }
        pa[ks] = U.v;
      }

      // ---- O += P @ V ----
#pragma unroll
      for (int ks = 0; ks < 2; ks++)
#pragma unroll
        for (int dt = 0; dt < 4; dt++) {
          s16x8 vb2 = *(const s16x8*)&Vt[cur][dt * 16 + lr][(((ks * 4 + lg) ^ lr) & 7) * 8];
          o[j][dt] = __builtin_amdgcn_mfma_f32_16x16x32_bf16(
              asbf(pa[ks]), asbf(vb2), o[j][dt], 0, 0, 0);
        }
    }

    __syncthreads();
  }

  // epilogue: reduce lsum over the 4 lanes sharing each q, divide, write Y
#pragma unroll
  for (int j = 0; j < 2; j++) {
    float tot = lsum[j];
    tot += __shfl_xor(tot, 16, 64);
    tot += __shfl_xor(tot, 32, 64);
#pragma unroll
    for (int r = 0; r < 4; r++) {
      float inv = 1.0f / __shfl(tot, lg * 4 + r, 64);
      int qrow = b * T + q0 + j * 64 + wid * 16 + lg * 4 + r;
#pragma unroll
      for (int dt = 0; dt < 4; dt++) {
        int col = hc + dt * 16 + lr;
        int cb = col >> 3;
        int cs = (cb & ~7) | ((cb ^ qrow) & 7);
        Y[(size_t)qrow * C + cs * 8 + (col & 7)] = f2bf(o[j][dt][r] * inv);
      }
    }
  }
}

// ---------------------------------------------------------------------------
extern "C" void kernel_launch(void* const* d_in, const int* in_sizes, int n_in,
                              void* d_out, int out_size, void* d_ws, size_t ws_size,
                              hipStream_t stream) {
  const float* x   = (const float*)d_in[0];
  const float* ref = (const float*)d_in[1];
  const float* Wq  = (const float*)d_in[2];
  const float* bq  = (const float*)d_in[3];
  const float* Wk  = (const float*)d_in[4];
  const float* bk  = (const float*)d_in[5];
  const float* Wv  = (const float*)d_in[6];
  const float* bv  = (const float*)d_in[7];
  const float* Wrk = (const float*)d_in[8];
  const float* brk = (const float*)d_in[9];
  const float* Wrv = (const float*)d_in[10];
  const float* brv = (const float*)d_in[11];
  const float* Wp  = (const float*)d_in[12];
  const float* bp  = (const float*)d_in[13];
  float* out = (float*)d_out;

  char* ws = (char*)d_ws;
  auto alloc = [&](size_t bytes) {
    char* p = ws; ws += (bytes + 255) & ~(size_t)255; return p;
  };
  const size_t WB = (size_t)1024 * 1024 * 2;
  unsigned short* Wqkv = (unsigned short*)alloc(3 * WB);
  unsigned short* Wrkv = (unsigned short*)alloc(2 * WB);
  unsigned short* WpT  = (unsigned short*)alloc(WB);
  unsigned short* xg  = (unsigned short*)alloc((size_t)8192 * 1024 * 2);
  unsigned short* rg  = (unsigned short*)alloc((size_t)2048 * 1024 * 2);
  unsigned short* qb  = (unsigned short*)alloc((size_t)8192 * 1024 * 2);
  unsigned short* kb  = (unsigned short*)alloc((size_t)4 * 2560 * 1024 * 2);
  unsigned short* vbT = (unsigned short*)alloc((size_t)4096 * 2560 * 2);
  unsigned short* yb  = (unsigned short*)alloc((size_t)8192 * 1024 * 2);

  dim3 tb(256);
  dim3 tg(16, 16);
  wtrans<<<tg, tb, 0, stream>>>(Wq,  Wqkv);
  wtrans<<<tg, tb, 0, stream>>>(Wk,  Wqkv + (size_t)1024 * 1024);
  wtrans<<<tg, tb, 0, stream>>>(Wv,  Wqkv + (size_t)2048 * 1024);
  wtrans<<<tg, tb, 0, stream>>>(Wrk, Wrkv);
  wtrans<<<tg, tb, 0, stream>>>(Wrv, Wrkv + (size_t)1024 * 1024);
  wtrans<<<tg, tb, 0, stream>>>(Wp,  WpT);

  convswz<<<dim3(4096), tb, 0, stream>>>(x, xg);
  convswz<<<dim3(1024), tb, 0, stream>>>(ref, rg);

  gemm_bt<0><<<dim3(24, 64), tb, 0, stream>>>(xg, Wqkv, bq, bk, bv, qb, kb, vbT);
  gemm_bt<1><<<dim3(16, 16), tb, 0, stream>>>(rg, Wrkv, brk, brv, nullptr, kb, vbT, nullptr);

  attn<<<dim3(1024), tb, 0, stream>>>(qb, kb, vbT, yb);

  gemm_bt<2><<<dim3(8, 64), tb, 0, stream>>>(yb, WpT, bp, bp, bp, out, out, out);
}

// Round 6
// 290.395 us; speedup vs baseline: 2.1497x; 1.0185x over previous
//
#include <hip/hip_runtime.h>
#include <hip/hip_bf16.h>

typedef short s16x4 __attribute__((ext_vector_type(4)));
typedef short s16x8 __attribute__((ext_vector_type(8)));
typedef __bf16 bf16x8 __attribute__((ext_vector_type(8)));
typedef float f32x4 __attribute__((ext_vector_type(4)));

#define DEVI static __device__ __forceinline__

DEVI unsigned short f2bf(float x) {
  union { float f; unsigned u; } a; a.f = x;
  unsigned r = a.u + 0x7fffu + ((a.u >> 16) & 1u);
  return (unsigned short)(r >> 16);
}
DEVI float bf2f(unsigned short s) {
  union { unsigned u; float f; } a; a.u = ((unsigned)s) << 16; return a.f;
}
DEVI bf16x8 asbf(s16x8 v) {
  union { s16x8 s; bf16x8 b; } u; u.s = v; return u.b;
}
DEVI unsigned cvtpk(float lo, float hi) {
  unsigned r;
  asm("v_cvt_pk_bf16_f32 %0, %1, %2" : "=v"(r) : "v"(lo), "v"(hi));
  return r;
}
DEVI void gload16(const void* g, void* l) {
  __builtin_amdgcn_global_load_lds(
      (const __attribute__((address_space(1))) void*)g,
      (__attribute__((address_space(3))) void*)l, 16, 0, 0);
}

// ---------------------------------------------------------------------------
// Weight transpose + fp32->bf16, PRE-SWIZZLED for linear global_load_lds.
// ---------------------------------------------------------------------------
__global__ __launch_bounds__(256)
void wtrans(const float* __restrict__ W, unsigned short* __restrict__ WT) {
  __shared__ short tile[64][65];
  const int n0 = blockIdx.x * 64;
  const int k0 = blockIdx.y * 64;
  const int t = threadIdx.x;
#pragma unroll
  for (int i = 0; i < 4; i++) {
    int f = t + i * 256;
    int r = f >> 4, c = (f & 15) * 4;
    float4 v = *(const float4*)(W + (size_t)(k0 + r) * 1024 + n0 + c);
    tile[r][c + 0] = (short)f2bf(v.x);
    tile[r][c + 1] = (short)f2bf(v.y);
    tile[r][c + 2] = (short)f2bf(v.z);
    tile[r][c + 3] = (short)f2bf(v.w);
  }
  __syncthreads();
#pragma unroll
  for (int i = 0; i < 2; i++) {
    int f = t + i * 256;
    int r = f >> 3, c8 = f & 7;
    s16x8 o;
#pragma unroll
    for (int j = 0; j < 8; j++) o[j] = tile[c8 * 8 + j][r];
    *(s16x8*)(WT + (size_t)(n0 + r) * 1024 + k0 + ((c8 ^ (r & 7)) & 7) * 8) = o;
  }
}

// ---------------------------------------------------------------------------
// fp32 -> bf16 convert, pre-swizzled by row (within 64-col K-tiles).
// ---------------------------------------------------------------------------
__global__ __launch_bounds__(256)
void convswz(const float* __restrict__ X, unsigned short* __restrict__ Xg) {
  int f = blockIdx.x * 256 + threadIdx.x;
  int row = f >> 7, c8 = f & 127;
  const float* src = X + (size_t)row * 1024 + c8 * 8;
  float4 a = *(const float4*)src;
  float4 b2 = *(const float4*)(src + 4);
  s16x8 o;
  o[0] = (short)f2bf(a.x);  o[1] = (short)f2bf(a.y);
  o[2] = (short)f2bf(a.z);  o[3] = (short)f2bf(a.w);
  o[4] = (short)f2bf(b2.x); o[5] = (short)f2bf(b2.y);
  o[6] = (short)f2bf(b2.z); o[7] = (short)f2bf(b2.w);
  int cs = (c8 & ~7) | ((c8 ^ row) & 7);
  *(s16x8*)(Xg + (size_t)row * 1024 + cs * 8) = o;
}

// ---------------------------------------------------------------------------
// GEMM: A (bf16, pre-swizzled) @ BT (bf16, pre-swizzled) + bias.
// 128x128 tile, BK=64, 4 waves; global_load_lds width-16 staging.
// MODE 0: QKV fused (N=3072) -> qb | kb(swz) | vbT(transposed).
// MODE 1: refKV fused (N=2048) -> kb(swz) | vbT at s>=2048.
// MODE 2: proj (N=1024) -> fp32 out.
// ---------------------------------------------------------------------------
template<int MODE>
__global__ __launch_bounds__(256)
void gemm_bt(const unsigned short* __restrict__ A, const unsigned short* __restrict__ BT,
             const float* __restrict__ b0, const float* __restrict__ b1,
             const float* __restrict__ b2,
             void* __restrict__ o0, void* __restrict__ o1, void* __restrict__ o2)
{
  const int K = 1024;
  __shared__ __align__(16) short As[128][64];
  __shared__ __align__(16) short Bs[128][64];
  const int t = threadIdx.x;
  const int lane = t & 63, wid = t >> 6;
  const int wm = wid >> 1, wn = wid & 1;
  const int lr = lane & 15, lg = lane >> 4;
  const size_t m0 = (size_t)blockIdx.y * 128;
  const int n0 = blockIdx.x * 128;

  f32x4 acc[4][4];
#pragma unroll
  for (int i = 0; i < 4; i++)
#pragma unroll
    for (int j = 0; j < 4; j++) acc[i][j] = (f32x4){0.f, 0.f, 0.f, 0.f};

  const unsigned short* Abase = A + m0 * K;
  const unsigned short* Bbase = BT + (size_t)n0 * K;
  const int r_ld = t >> 3, cb_ld = t & 7;

  for (int k0 = 0; k0 < K; k0 += 64) {
#pragma unroll
    for (int i = 0; i < 4; i++) {
      int r = r_ld + i * 32;
      gload16(Abase + (size_t)r * K + k0 + cb_ld * 8,
              (short*)As + (i * 256 + wid * 64) * 8);
      gload16(Bbase + (size_t)r * K + k0 + cb_ld * 8,
              (short*)Bs + (i * 256 + wid * 64) * 8);
    }
    __syncthreads();
#pragma unroll
    for (int ks = 0; ks < 2; ks++) {
      s16x8 af[4], bfr[4];
#pragma unroll
      for (int i = 0; i < 4; i++)
        af[i] = *(const s16x8*)&As[wm * 64 + i * 16 + lr][(((ks * 4 + lg) ^ lr) & 7) * 8];
#pragma unroll
      for (int i = 0; i < 4; i++)
        bfr[i] = *(const s16x8*)&Bs[wn * 64 + i * 16 + lr][(((ks * 4 + lg) ^ lr) & 7) * 8];
#pragma unroll
      for (int mi = 0; mi < 4; mi++)
#pragma unroll
        for (int ni = 0; ni < 4; ni++)
          acc[mi][ni] = __builtin_amdgcn_mfma_f32_16x16x32_bf16(
              asbf(af[mi]), asbf(bfr[ni]), acc[mi][ni], 0, 0, 0);
    }
    __syncthreads();
  }

  const int seg = n0 >> 10;
  const float* bb = (seg == 0) ? b0 : (seg == 1 ? b1 : b2);
#pragma unroll
  for (int mi = 0; mi < 4; mi++) {
#pragma unroll
    for (int ni = 0; ni < 4; ni++) {
      int cg = n0 + wn * 64 + ni * 16 + lr;
      int c = cg & 1023;
      float bv = bb[c];
      const bool vseg = (MODE == 0 && seg == 2) || (MODE == 1 && seg == 1);
      if (MODE != 2 && vseg) {
        // transposed V: vbT[(b*16+h)*64 + d][2560], pre-swizzled per 64-s tile
        int rm0 = (int)m0 + wm * 64 + mi * 16 + lg * 4;
        int d = c & 63, hh = c >> 6;
        int bb_, s;
        if (MODE == 0) { bb_ = rm0 >> 11; s = rm0 & 2047; }
        else           { bb_ = rm0 >> 9;  s = 2048 + (rm0 & 511); }
        int scol = (s & ~63) + ((((s >> 3) ^ d) & 7) << 3) + (s & 7);
        unsigned short* dst = (unsigned short*)(MODE == 0 ? o2 : o1);
        short4 pk4;
        pk4.x = (short)f2bf(acc[mi][ni][0] + bv);
        pk4.y = (short)f2bf(acc[mi][ni][1] + bv);
        pk4.z = (short)f2bf(acc[mi][ni][2] + bv);
        pk4.w = (short)f2bf(acc[mi][ni][3] + bv);
        *(short4*)(dst + ((size_t)(bb_ * 16 + hh) * 64 + d) * 2560 + scol) = pk4;
      } else {
#pragma unroll
        for (int r = 0; r < 4; r++) {
          int rm = (int)m0 + wm * 64 + mi * 16 + lg * 4 + r;
          float val = acc[mi][ni][r] + bv;
          if (MODE == 2) {
            ((float*)o0)[(size_t)rm * 1024 + cg] = val;
          } else {
            size_t orow; unsigned short* dst; bool swz;
            if (MODE == 0) {
              if (seg == 0) { dst = (unsigned short*)o0; orow = rm; swz = false; }
              else { orow = (size_t)(rm >> 11) * 2560 + (rm & 2047);
                     dst = (unsigned short*)o1; swz = true; }
            } else {
              orow = (size_t)(rm >> 9) * 2560 + 2048 + (rm & 511);
              dst = (unsigned short*)o0; swz = true;
            }
            int cc = c;
            if (swz) cc = (c & ~63) | ((((c >> 3) ^ (int)orow) & 7) << 3) | (c & 7);
            dst[orow * 1024 + cc] = f2bf(val);
          }
        }
      }
    }
  }
}

// ---------------------------------------------------------------------------
// Flash attention v6: QBLK=128, shared K/V fragment loads across both
// q-subtiles (halves ds_read_b128), setprio around MFMA clusters.
// ---------------------------------------------------------------------------
__global__ __launch_bounds__(256, 4)
void attn(const unsigned short* __restrict__ Q, const unsigned short* __restrict__ Kb,
          const unsigned short* __restrict__ VbT, unsigned short* __restrict__ Y)
{
  const int T = 2048, S = 2560, C = 1024, TREF = 512;
  __shared__ __align__(16) short Ks[2][64][64];
  __shared__ __align__(16) short Vt[2][64][64];   // Vt[d][s]
  const int t = threadIdx.x;
  const int lane = t & 63, wid = t >> 6;
  const int lr = lane & 15, lg = lane >> 4;

  // XCD-aware remap: 1024 blocks; all 16 q-blocks of a (b,h) on one XCD.
  const int bid = blockIdx.x;
  const int xcd = bid & 7, idx = bid >> 3;
  const int bh = xcd * 8 + (idx >> 4);
  const int bx = idx & 15;
  const int q0 = bx * 128;
  const int b = bh >> 4;
  const int hc = (bh & 15) * 64;

  // Q fragments for both subtiles, scaled by (1/8)*log2(e)
  const float QSC = 0.125f * 1.44269504088896f;
  s16x8 qf[2][2];
#pragma unroll
  for (int j = 0; j < 2; j++) {
    size_t qrow = (size_t)(b * T + q0 + j * 64 + wid * 16 + lr);
#pragma unroll
    for (int ks = 0; ks < 2; ks++) {
      s16x8 v = *(const s16x8*)(Q + qrow * C + hc + ks * 32 + lg * 8);
#pragma unroll
      for (int jj = 0; jj < 8; jj++)
        v[jj] = (short)f2bf(bf2f((unsigned short)v[jj]) * QSC);
      qf[j][ks] = v;
    }
  }

  float mrow[2] = {-1e30f, -1e30f}, lsum[2] = {0.f, 0.f};
  f32x4 o[2][4];
#pragma unroll
  for (int j = 0; j < 2; j++)
#pragma unroll
    for (int d = 0; d < 4; d++) o[j][d] = (f32x4){0.f, 0.f, 0.f, 0.f};

  const int self_tiles = 2 * bx + 2;
  const int ntiles = self_tiles + TREF / 64;

  auto s0_of = [&](int ti2) {
    return (ti2 < self_tiles) ? ti2 * 64 : T + (ti2 - self_tiles) * 64;
  };
  const int r_ld = t >> 3, cb_ld = t & 7;
  auto load_K = [&](int ti2, int buf) {
    int s0 = s0_of(ti2);
    const unsigned short* Krow = Kb + (size_t)(b * S + s0) * C + hc;
#pragma unroll
    for (int i = 0; i < 2; i++)
      gload16(Krow + (size_t)(r_ld + i * 32) * C + cb_ld * 8,
              (short*)&Ks[buf][0][0] + (i * 256 + wid * 64) * 8);
  };
  auto load_V = [&](int ti2, int buf) {
    int s0 = s0_of(ti2);
    const unsigned short* Vr = VbT + (size_t)bh * 64 * S + s0;
#pragma unroll
    for (int i = 0; i < 2; i++)
      gload16(Vr + (size_t)(r_ld + i * 32) * S + cb_ld * 8,
              (short*)&Vt[buf][0][0] + (i * 256 + wid * 64) * 8);
  };

  load_K(0, 0);
  load_V(0, 0);
  __syncthreads();

  for (int ti = 0; ti < ntiles; ti++) {
    const int cur = ti & 1;
    const bool more = (ti + 1 < ntiles);
    if (more) { load_K(ti + 1, cur ^ 1); load_V(ti + 1, cur ^ 1); }

    // subtile-0 contributes nothing at the tile just above its diagonal
    const bool act0 = !(ti == 2 * bx + 1);

    // ---- S^T = K Q^T for BOTH subtiles, shared K fragments ----
    f32x4 sa[2][4];
#pragma unroll
    for (int j = 0; j < 2; j++)
#pragma unroll
      for (int nt = 0; nt < 4; nt++) sa[j][nt] = (f32x4){0.f, 0.f, 0.f, 0.f};
    __builtin_amdgcn_s_setprio(1);
#pragma unroll
    for (int ks = 0; ks < 2; ks++) {
      s16x8 kf[4];
#pragma unroll
      for (int nt = 0; nt < 4; nt++)
        kf[nt] = *(const s16x8*)&Ks[cur][nt * 16 + lr][(((ks * 4 + lg) ^ lr) & 7) * 8];
#pragma unroll
      for (int nt = 0; nt < 4; nt++) {
        sa[0][nt] = __builtin_amdgcn_mfma_f32_16x16x32_bf16(
            asbf(kf[nt]), asbf(qf[0][ks]), sa[0][nt], 0, 0, 0);
        sa[1][nt] = __builtin_amdgcn_mfma_f32_16x16x32_bf16(
            asbf(kf[nt]), asbf(qf[1][ks]), sa[1][nt], 0, 0, 0);
      }
    }
    __builtin_amdgcn_s_setprio(0);

    // ---- per-subtile mask + softmax + P-pack ----
    s16x8 pa[2][2];
#pragma unroll
    for (int j = 0; j < 2; j++) {
      if (j == 0 && !act0) continue;

      if (ti == 2 * bx + j) {   // diagonal tile for subtile j
        int qg = wid * 16 + lr;
#pragma unroll
        for (int nt = 0; nt < 4; nt++)
#pragma unroll
          for (int r = 0; r < 4; r++)
            if (nt * 16 + lg * 4 + r > qg) sa[j][nt][r] = -1e30f;
      }

      float lm = sa[j][0][0];
#pragma unroll
      for (int nt = 0; nt < 4; nt++)
#pragma unroll
        for (int r = 0; r < 4; r++) lm = fmaxf(lm, sa[j][nt][r]);
      if (!__all(lm <= mrow[j] + 8.f)) {
        float tm = lm;
        tm = fmaxf(tm, __shfl_xor(tm, 16, 64));
        tm = fmaxf(tm, __shfl_xor(tm, 32, 64));
        float mn = fmaxf(mrow[j], tm);
        float alpha = __builtin_amdgcn_exp2f(mrow[j] - mn);
        mrow[j] = mn;
        lsum[j] *= alpha;
#pragma unroll
        for (int r = 0; r < 4; r++) {
          float ar = __shfl(alpha, lg * 4 + r, 64);
#pragma unroll
          for (int dt = 0; dt < 4; dt++) o[j][dt][r] *= ar;
        }
      }

      unsigned pk2[4][2];
      float rs = 0.f;
#pragma unroll
      for (int nt = 0; nt < 4; nt++) {
        float p0 = __builtin_amdgcn_exp2f(sa[j][nt][0] - mrow[j]);
        float p1 = __builtin_amdgcn_exp2f(sa[j][nt][1] - mrow[j]);
        float p2 = __builtin_amdgcn_exp2f(sa[j][nt][2] - mrow[j]);
        float p3 = __builtin_amdgcn_exp2f(sa[j][nt][3] - mrow[j]);
        rs += (p0 + p1) + (p2 + p3);
        pk2[nt][0] = cvtpk(p0, p1);
        pk2[nt][1] = cvtpk(p2, p3);
      }
      lsum[j] += rs;

      // in-register exchange: build PA fragments (row=q=lr, k=s)
#pragma unroll
      for (int ks = 0; ks < 2; ks++) {
        union { unsigned w[4]; s16x8 v; } U;
#pragma unroll
        for (int w = 0; w < 4; w++) {
          int srcL = lr + (((lg & 1) * 2 + (w >> 1)) << 4);
          unsigned v0 = __shfl((int)pk2[2 * ks][w & 1], srcL, 64);
          unsigned v1 = __shfl((int)pk2[2 * ks + 1][w & 1], srcL, 64);
          U.w[w] = (lg & 2) ? v1 : v0;
        }
        pa[j][ks] = U.v;
      }
    }

    // ---- O += P @ V for BOTH subtiles, shared V fragments ----
    __builtin_amdgcn_s_setprio(1);
#pragma unroll
    for (int ks = 0; ks < 2; ks++) {
      s16x8 vf[4];
#pragma unroll
      for (int dt = 0; dt < 4; dt++)
        vf[dt] = *(const s16x8*)&Vt[cur][dt * 16 + lr][(((ks * 4 + lg) ^ lr) & 7) * 8];
#pragma unroll
      for (int dt = 0; dt < 4; dt++) {
        if (act0)
          o[0][dt] = __builtin_amdgcn_mfma_f32_16x16x32_bf16(
              asbf(pa[0][ks]), asbf(vf[dt]), o[0][dt], 0, 0, 0);
        o[1][dt] = __builtin_amdgcn_mfma_f32_16x16x32_bf16(
            asbf(pa[1][ks]), asbf(vf[dt]), o[1][dt], 0, 0, 0);
      }
    }
    __builtin_amdgcn_s_setprio(0);

    __syncthreads();
  }

  // epilogue: reduce lsum over the 4 lanes sharing each q, divide, write Y
#pragma unroll
  for (int j = 0; j < 2; j++) {
    float tot = lsum[j];
    tot += __shfl_xor(tot, 16, 64);
    tot += __shfl_xor(tot, 32, 64);
#pragma unroll
    for (int r = 0; r < 4; r++) {
      float inv = 1.0f / __shfl(tot, lg * 4 + r, 64);
      int qrow = b * T + q0 + j * 64 + wid * 16 + lg * 4 + r;
#pragma unroll
      for (int dt = 0; dt < 4; dt++) {
        int col = hc + dt * 16 + lr;
        int cb = col >> 3;
        int cs = (cb & ~7) | ((cb ^ qrow) & 7);
        Y[(size_t)qrow * C + cs * 8 + (col & 7)] = f2bf(o[j][dt][r] * inv);
      }
    }
  }
}

// ---------------------------------------------------------------------------
extern "C" void kernel_launch(void* const* d_in, const int* in_sizes, int n_in,
                              void* d_out, int out_size, void* d_ws, size_t ws_size,
                              hipStream_t stream) {
  const float* x   = (const float*)d_in[0];
  const float* ref = (const float*)d_in[1];
  const float* Wq  = (const float*)d_in[2];
  const float* bq  = (const float*)d_in[3];
  const float* Wk  = (const float*)d_in[4];
  const float* bk  = (const float*)d_in[5];
  const float* Wv  = (const float*)d_in[6];
  const float* bv  = (const float*)d_in[7];
  const float* Wrk = (const float*)d_in[8];
  const float* brk = (const float*)d_in[9];
  const float* Wrv = (const float*)d_in[10];
  const float* brv = (const float*)d_in[11];
  const float* Wp  = (const float*)d_in[12];
  const float* bp  = (const float*)d_in[13];
  float* out = (float*)d_out;

  char* ws = (char*)d_ws;
  auto alloc = [&](size_t bytes) {
    char* p = ws; ws += (bytes + 255) & ~(size_t)255; return p;
  };
  const size_t WB = (size_t)1024 * 1024 * 2;
  unsigned short* Wqkv = (unsigned short*)alloc(3 * WB);
  unsigned short* Wrkv = (unsigned short*)alloc(2 * WB);
  unsigned short* WpT  = (unsigned short*)alloc(WB);
  unsigned short* xg  = (unsigned short*)alloc((size_t)8192 * 1024 * 2);
  unsigned short* rg  = (unsigned short*)alloc((size_t)2048 * 1024 * 2);
  unsigned short* qb  = (unsigned short*)alloc((size_t)8192 * 1024 * 2);
  unsigned short* kb  = (unsigned short*)alloc((size_t)4 * 2560 * 1024 * 2);
  unsigned short* vbT = (unsigned short*)alloc((size_t)4096 * 2560 * 2);
  unsigned short* yb  = (unsigned short*)alloc((size_t)8192 * 1024 * 2);

  dim3 tb(256);
  dim3 tg(16, 16);
  wtrans<<<tg, tb, 0, stream>>>(Wq,  Wqkv);
  wtrans<<<tg, tb, 0, stream>>>(Wk,  Wqkv + (size_t)1024 * 1024);
  wtrans<<<tg, tb, 0, stream>>>(Wv,  Wqkv + (size_t)2048 * 1024);
  wtrans<<<tg, tb, 0, stream>>>(Wrk, Wrkv);
  wtrans<<<tg, tb, 0, stream>>>(Wrv, Wrkv + (size_t)1024 * 1024);
  wtrans<<<tg, tb, 0, stream>>>(Wp,  WpT);

  convswz<<<dim3(4096), tb, 0, stream>>>(x, xg);
  convswz<<<dim3(1024), tb, 0, stream>>>(ref, rg);

  gemm_bt<0><<<dim3(24, 64), tb, 0, stream>>>(xg, Wqkv, bq, bk, bv, qb, kb, vbT);
  gemm_bt<1><<<dim3(16, 16), tb, 0, stream>>>(rg, Wrkv, brk, brv, nullptr, kb, vbT, nullptr);

  attn<<<dim3(1024), tb, 0, stream>>>(qb, kb, vbT, yb);

  gemm_bt<2><<<dim3(8, 64), tb, 0, stream>>>(yb, WpT, bp, bp, bp, out, out, out);
}

// Round 7
// 242.673 us; speedup vs baseline: 2.5725x; 1.1967x over previous
//
#include <hip/hip_runtime.h>
#include <hip/hip_bf16.h>

typedef short s16x4 __attribute__((ext_vector_type(4)));
typedef short s16x8 __attribute__((ext_vector_type(8)));
typedef __bf16 bf16x8 __attribute__((ext_vector_type(8)));
typedef float f32x4 __attribute__((ext_vector_type(4)));

#define DEVI static __device__ __forceinline__

DEVI unsigned short f2bf(float x) {
  union { float f; unsigned u; } a; a.f = x;
  unsigned r = a.u + 0x7fffu + ((a.u >> 16) & 1u);
  return (unsigned short)(r >> 16);
}
DEVI float bf2f(unsigned short s) {
  union { unsigned u; float f; } a; a.u = ((unsigned)s) << 16; return a.f;
}
DEVI bf16x8 asbf(s16x8 v) {
  union { s16x8 s; bf16x8 b; } u; u.s = v; return u.b;
}
DEVI unsigned cvtpk(float lo, float hi) {
  unsigned r;
  asm("v_cvt_pk_bf16_f32 %0, %1, %2" : "=v"(r) : "v"(lo), "v"(hi));
  return r;
}
DEVI void gload16(const void* g, void* l) {
  __builtin_amdgcn_global_load_lds(
      (const __attribute__((address_space(1))) void*)g,
      (__attribute__((address_space(3))) void*)l, 16, 0, 0);
}

// ---------------------------------------------------------------------------
// 6x weight transpose + fp32->bf16, PRE-SWIZZLED, one launch (z = weight id).
// ---------------------------------------------------------------------------
struct W6 { const float* w[6]; unsigned short* o[6]; };

__global__ __launch_bounds__(256)
void wtrans6(W6 p) {
  __shared__ short tile[64][65];
  const float* __restrict__ W = p.w[blockIdx.z];
  unsigned short* __restrict__ WT = p.o[blockIdx.z];
  const int n0 = blockIdx.x * 64;
  const int k0 = blockIdx.y * 64;
  const int t = threadIdx.x;
#pragma unroll
  for (int i = 0; i < 4; i++) {
    int f = t + i * 256;
    int r = f >> 4, c = (f & 15) * 4;
    float4 v = *(const float4*)(W + (size_t)(k0 + r) * 1024 + n0 + c);
    tile[r][c + 0] = (short)f2bf(v.x);
    tile[r][c + 1] = (short)f2bf(v.y);
    tile[r][c + 2] = (short)f2bf(v.z);
    tile[r][c + 3] = (short)f2bf(v.w);
  }
  __syncthreads();
#pragma unroll
  for (int i = 0; i < 2; i++) {
    int f = t + i * 256;
    int r = f >> 3, c8 = f & 7;
    s16x8 o;
#pragma unroll
    for (int j = 0; j < 8; j++) o[j] = tile[c8 * 8 + j][r];
    *(s16x8*)(WT + (size_t)(n0 + r) * 1024 + k0 + ((c8 ^ (r & 7)) & 7) * 8) = o;
  }
}

// ---------------------------------------------------------------------------
// fp32 -> bf16 convert (x then ref), pre-swizzled, one launch.
// ---------------------------------------------------------------------------
__global__ __launch_bounds__(256)
void convswz2(const float* __restrict__ X, const float* __restrict__ R,
              unsigned short* __restrict__ Xg) {
  int f = blockIdx.x * 256 + threadIdx.x;
  int row = f >> 7, c8 = f & 127;
  const float* src = (row < 8192 ? X + (size_t)row * 1024
                                 : R + (size_t)(row - 8192) * 1024) + c8 * 8;
  float4 a = *(const float4*)src;
  float4 b2 = *(const float4*)(src + 4);
  s16x8 o;
  o[0] = (short)f2bf(a.x);  o[1] = (short)f2bf(a.y);
  o[2] = (short)f2bf(a.z);  o[3] = (short)f2bf(a.w);
  o[4] = (short)f2bf(b2.x); o[5] = (short)f2bf(b2.y);
  o[6] = (short)f2bf(b2.z); o[7] = (short)f2bf(b2.w);
  int cs = (c8 & ~7) | ((c8 ^ row) & 7);
  *(s16x8*)(Xg + (size_t)row * 1024 + cs * 8) = o;
}

// ---------------------------------------------------------------------------
// GEMM: A (bf16, pre-swizzled) @ BT (bf16, pre-swizzled) + bias.
// 128x128 tile, BK=64, 4 waves; global_load_lds width-16 staging.
// MODE 0: QKV fused (N=3072) -> qb | kb(swz) | vbT(transposed).
// MODE 1: refKV fused (N=2048) -> kb(swz) | vbT at s>=2048.
// MODE 2: proj (N=1024) -> fp32 out.
// ---------------------------------------------------------------------------
template<int MODE>
__global__ __launch_bounds__(256)
void gemm_bt(const unsigned short* __restrict__ A, const unsigned short* __restrict__ BT,
             const float* __restrict__ b0, const float* __restrict__ b1,
             const float* __restrict__ b2,
             void* __restrict__ o0, void* __restrict__ o1, void* __restrict__ o2)
{
  const int K = 1024;
  __shared__ __align__(16) short As[128][64];
  __shared__ __align__(16) short Bs[128][64];
  const int t = threadIdx.x;
  const int lane = t & 63, wid = t >> 6;
  const int wm = wid >> 1, wn = wid & 1;
  const int lr = lane & 15, lg = lane >> 4;
  const size_t m0 = (size_t)blockIdx.y * 128;
  const int n0 = blockIdx.x * 128;

  f32x4 acc[4][4];
#pragma unroll
  for (int i = 0; i < 4; i++)
#pragma unroll
    for (int j = 0; j < 4; j++) acc[i][j] = (f32x4){0.f, 0.f, 0.f, 0.f};

  const unsigned short* Abase = A + m0 * K;
  const unsigned short* Bbase = BT + (size_t)n0 * K;
  const int r_ld = t >> 3, cb_ld = t & 7;

  for (int k0 = 0; k0 < K; k0 += 64) {
#pragma unroll
    for (int i = 0; i < 4; i++) {
      int r = r_ld + i * 32;
      gload16(Abase + (size_t)r * K + k0 + cb_ld * 8,
              (short*)As + (i * 256 + wid * 64) * 8);
      gload16(Bbase + (size_t)r * K + k0 + cb_ld * 8,
              (short*)Bs + (i * 256 + wid * 64) * 8);
    }
    __syncthreads();
#pragma unroll
    for (int ks = 0; ks < 2; ks++) {
      s16x8 af[4], bfr[4];
#pragma unroll
      for (int i = 0; i < 4; i++)
        af[i] = *(const s16x8*)&As[wm * 64 + i * 16 + lr][(((ks * 4 + lg) ^ lr) & 7) * 8];
#pragma unroll
      for (int i = 0; i < 4; i++)
        bfr[i] = *(const s16x8*)&Bs[wn * 64 + i * 16 + lr][(((ks * 4 + lg) ^ lr) & 7) * 8];
#pragma unroll
      for (int mi = 0; mi < 4; mi++)
#pragma unroll
        for (int ni = 0; ni < 4; ni++)
          acc[mi][ni] = __builtin_amdgcn_mfma_f32_16x16x32_bf16(
              asbf(af[mi]), asbf(bfr[ni]), acc[mi][ni], 0, 0, 0);
    }
    __syncthreads();
  }

  const int seg = n0 >> 10;
  const float* bb = (seg == 0) ? b0 : (seg == 1 ? b1 : b2);
#pragma unroll
  for (int mi = 0; mi < 4; mi++) {
#pragma unroll
    for (int ni = 0; ni < 4; ni++) {
      int cg = n0 + wn * 64 + ni * 16 + lr;
      int c = cg & 1023;
      float bv = bb[c];
      const bool vseg = (MODE == 0 && seg == 2) || (MODE == 1 && seg == 1);
      if (MODE != 2 && vseg) {
        // transposed V: vbT[(b*16+h)*64 + d][2560], pre-swizzled per 64-s tile
        int rm0 = (int)m0 + wm * 64 + mi * 16 + lg * 4;
        int d = c & 63, hh = c >> 6;
        int bb_, s;
        if (MODE == 0) { bb_ = rm0 >> 11; s = rm0 & 2047; }
        else           { bb_ = rm0 >> 9;  s = 2048 + (rm0 & 511); }
        int scol = (s & ~63) + ((((s >> 3) ^ d) & 7) << 3) + (s & 7);
        unsigned short* dst = (unsigned short*)(MODE == 0 ? o2 : o1);
        short4 pk4;
        pk4.x = (short)f2bf(acc[mi][ni][0] + bv);
        pk4.y = (short)f2bf(acc[mi][ni][1] + bv);
        pk4.z = (short)f2bf(acc[mi][ni][2] + bv);
        pk4.w = (short)f2bf(acc[mi][ni][3] + bv);
        *(short4*)(dst + ((size_t)(bb_ * 16 + hh) * 64 + d) * 2560 + scol) = pk4;
      } else {
#pragma unroll
        for (int r = 0; r < 4; r++) {
          int rm = (int)m0 + wm * 64 + mi * 16 + lg * 4 + r;
          float val = acc[mi][ni][r] + bv;
          if (MODE == 2) {
            ((float*)o0)[(size_t)rm * 1024 + cg] = val;
          } else {
            size_t orow; unsigned short* dst; bool swz;
            if (MODE == 0) {
              if (seg == 0) { dst = (unsigned short*)o0; orow = rm; swz = false; }
              else { orow = (size_t)(rm >> 11) * 2560 + (rm & 2047);
                     dst = (unsigned short*)o1; swz = true; }
            } else {
              orow = (size_t)(rm >> 9) * 2560 + 2048 + (rm & 511);
              dst = (unsigned short*)o0; swz = true;
            }
            int cc = c;
            if (swz) cc = (c & ~63) | ((((c >> 3) ^ (int)orow) & 7) << 3) | (c & 7);
            dst[orow * 1024 + cc] = f2bf(val);
          }
        }
      }
    }
  }
}

// ---------------------------------------------------------------------------
// Flash attention v7: diagonally-paired q-tiles (bx, 31-bx) -> constant
// 49 subtile-tile activations per block (perfect MFMA balance), shared
// K/V fragments across subtiles, per-subtile activity guards.
// ---------------------------------------------------------------------------
__global__ __launch_bounds__(256, 4)
void attn(const unsigned short* __restrict__ Q, const unsigned short* __restrict__ Kb,
          const unsigned short* __restrict__ VbT, unsigned short* __restrict__ Y)
{
  const int T = 2048, S = 2560, C = 1024, TREF = 512;
  __shared__ __align__(16) short Ks[2][64][64];
  __shared__ __align__(16) short Vt[2][64][64];   // Vt[d][s]
  const int t = threadIdx.x;
  const int lane = t & 63, wid = t >> 6;
  const int lr = lane & 15, lg = lane >> 4;

  // XCD-aware remap: all 16 blocks of a (b,h) on one XCD.
  const int bid = blockIdx.x;
  const int xcd = bid & 7, idx = bid >> 3;
  const int bh = xcd * 8 + (idx >> 4);
  const int bx = idx & 15;
  const int b = bh >> 4;
  const int hc = (bh & 15) * 64;
  const int qt[2] = {bx, 31 - bx};   // paired q-tiles (64 rows each)

  // Q fragments for both subtiles, scaled by (1/8)*log2(e)
  const float QSC = 0.125f * 1.44269504088896f;
  s16x8 qf[2][2];
#pragma unroll
  for (int j = 0; j < 2; j++) {
    size_t qrow = (size_t)(b * T + qt[j] * 64 + wid * 16 + lr);
#pragma unroll
    for (int ks = 0; ks < 2; ks++) {
      s16x8 v = *(const s16x8*)(Q + qrow * C + hc + ks * 32 + lg * 8);
#pragma unroll
      for (int jj = 0; jj < 8; jj++)
        v[jj] = (short)f2bf(bf2f((unsigned short)v[jj]) * QSC);
      qf[j][ks] = v;
    }
  }

  float mrow[2] = {-1e30f, -1e30f}, lsum[2] = {0.f, 0.f};
  f32x4 o[2][4];
#pragma unroll
  for (int j = 0; j < 2; j++)
#pragma unroll
    for (int d = 0; d < 4; d++) o[j][d] = (f32x4){0.f, 0.f, 0.f, 0.f};

  const int nself = 32 - bx;           // self tiles 0 .. 31-bx
  const int ntiles = nself + TREF / 64;

  auto s0_of = [&](int ti2) {
    return (ti2 < nself) ? ti2 * 64 : T + (ti2 - nself) * 64;
  };
  const int r_ld = t >> 3, cb_ld = t & 7;
  auto load_K = [&](int ti2, int buf) {
    int s0 = s0_of(ti2);
    const unsigned short* Krow = Kb + (size_t)(b * S + s0) * C + hc;
#pragma unroll
    for (int i = 0; i < 2; i++)
      gload16(Krow + (size_t)(r_ld + i * 32) * C + cb_ld * 8,
              (short*)&Ks[buf][0][0] + (i * 256 + wid * 64) * 8);
  };
  auto load_V = [&](int ti2, int buf) {
    int s0 = s0_of(ti2);
    const unsigned short* Vr = VbT + (size_t)bh * 64 * S + s0;
#pragma unroll
    for (int i = 0; i < 2; i++)
      gload16(Vr + (size_t)(r_ld + i * 32) * S + cb_ld * 8,
              (short*)&Vt[buf][0][0] + (i * 256 + wid * 64) * 8);
  };

  load_K(0, 0);
  load_V(0, 0);
  __syncthreads();

  for (int ti = 0; ti < ntiles; ti++) {
    const int cur = ti & 1;
    const bool more = (ti + 1 < ntiles);
    if (more) { load_K(ti + 1, cur ^ 1); load_V(ti + 1, cur ^ 1); }

    // activity: subtile0 (early q-tile) sees tiles 0..bx + refs;
    // subtile1 (late q-tile) sees every staged tile.
    const bool a0 = (ti <= bx) || (ti >= nself);

    // ---- S^T = K Q^T, shared K fragments ----
    f32x4 sa[2][4];
#pragma unroll
    for (int j = 0; j < 2; j++)
#pragma unroll
      for (int nt = 0; nt < 4; nt++) sa[j][nt] = (f32x4){0.f, 0.f, 0.f, 0.f};
    __builtin_amdgcn_s_setprio(1);
#pragma unroll
    for (int ks = 0; ks < 2; ks++) {
      s16x8 kf[4];
#pragma unroll
      for (int nt = 0; nt < 4; nt++)
        kf[nt] = *(const s16x8*)&Ks[cur][nt * 16 + lr][(((ks * 4 + lg) ^ lr) & 7) * 8];
#pragma unroll
      for (int nt = 0; nt < 4; nt++) {
        if (a0)
          sa[0][nt] = __builtin_amdgcn_mfma_f32_16x16x32_bf16(
              asbf(kf[nt]), asbf(qf[0][ks]), sa[0][nt], 0, 0, 0);
        sa[1][nt] = __builtin_amdgcn_mfma_f32_16x16x32_bf16(
            asbf(kf[nt]), asbf(qf[1][ks]), sa[1][nt], 0, 0, 0);
      }
    }
    __builtin_amdgcn_s_setprio(0);

    // ---- per-subtile mask + softmax + P-pack ----
    s16x8 pa[2][2];
#pragma unroll
    for (int j = 0; j < 2; j++) {
      if (j == 0 && !a0) continue;

      if (ti == (j == 0 ? bx : nself - 1)) {   // diagonal tile for subtile j
        int qg = wid * 16 + lr;
#pragma unroll
        for (int nt = 0; nt < 4; nt++)
#pragma unroll
          for (int r = 0; r < 4; r++)
            if (nt * 16 + lg * 4 + r > qg) sa[j][nt][r] = -1e30f;
      }

      float lm = sa[j][0][0];
#pragma unroll
      for (int nt = 0; nt < 4; nt++)
#pragma unroll
        for (int r = 0; r < 4; r++) lm = fmaxf(lm, sa[j][nt][r]);
      if (!__all(lm <= mrow[j] + 8.f)) {
        float tm = lm;
        tm = fmaxf(tm, __shfl_xor(tm, 16, 64));
        tm = fmaxf(tm, __shfl_xor(tm, 32, 64));
        float mn = fmaxf(mrow[j], tm);
        float alpha = __builtin_amdgcn_exp2f(mrow[j] - mn);
        mrow[j] = mn;
        lsum[j] *= alpha;
#pragma unroll
        for (int r = 0; r < 4; r++) {
          float ar = __shfl(alpha, lg * 4 + r, 64);
#pragma unroll
          for (int dt = 0; dt < 4; dt++) o[j][dt][r] *= ar;
        }
      }

      unsigned pk2[4][2];
      float rs = 0.f;
#pragma unroll
      for (int nt = 0; nt < 4; nt++) {
        float p0 = __builtin_amdgcn_exp2f(sa[j][nt][0] - mrow[j]);
        float p1 = __builtin_amdgcn_exp2f(sa[j][nt][1] - mrow[j]);
        float p2 = __builtin_amdgcn_exp2f(sa[j][nt][2] - mrow[j]);
        float p3 = __builtin_amdgcn_exp2f(sa[j][nt][3] - mrow[j]);
        rs += (p0 + p1) + (p2 + p3);
        pk2[nt][0] = cvtpk(p0, p1);
        pk2[nt][1] = cvtpk(p2, p3);
      }
      lsum[j] += rs;

      // in-register exchange: build PA fragments (row=q=lr, k=s)
#pragma unroll
      for (int ks = 0; ks < 2; ks++) {
        union { unsigned w[4]; s16x8 v; } U;
#pragma unroll
        for (int w = 0; w < 4; w++) {
          int srcL = lr + (((lg & 1) * 2 + (w >> 1)) << 4);
          unsigned v0 = __shfl((int)pk2[2 * ks][w & 1], srcL, 64);
          unsigned v1 = __shfl((int)pk2[2 * ks + 1][w & 1], srcL, 64);
          U.w[w] = (lg & 2) ? v1 : v0;
        }
        pa[j][ks] = U.v;
      }
    }

    // ---- O += P @ V, shared V fragments ----
    __builtin_amdgcn_s_setprio(1);
#pragma unroll
    for (int ks = 0; ks < 2; ks++) {
      s16x8 vf[4];
#pragma unroll
      for (int dt = 0; dt < 4; dt++)
        vf[dt] = *(const s16x8*)&Vt[cur][dt * 16 + lr][(((ks * 4 + lg) ^ lr) & 7) * 8];
#pragma unroll
      for (int dt = 0; dt < 4; dt++) {
        if (a0)
          o[0][dt] = __builtin_amdgcn_mfma_f32_16x16x32_bf16(
              asbf(pa[0][ks]), asbf(vf[dt]), o[0][dt], 0, 0, 0);
        o[1][dt] = __builtin_amdgcn_mfma_f32_16x16x32_bf16(
            asbf(pa[1][ks]), asbf(vf[dt]), o[1][dt], 0, 0, 0);
      }
    }
    __builtin_amdgcn_s_setprio(0);

    __syncthreads();
  }

  // epilogue: reduce lsum over the 4 lanes sharing each q, divide, write Y
#pragma unroll
  for (int j = 0; j < 2; j++) {
    float tot = lsum[j];
    tot += __shfl_xor(tot, 16, 64);
    tot += __shfl_xor(tot, 32, 64);
#pragma unroll
    for (int r = 0; r < 4; r++) {
      float inv = 1.0f / __shfl(tot, lg * 4 + r, 64);
      int qrow = b * T + qt[j] * 64 + wid * 16 + lg * 4 + r;
#pragma unroll
      for (int dt = 0; dt < 4; dt++) {
        int col = hc + dt * 16 + lr;
        int cb = col >> 3;
        int cs = (cb & ~7) | ((cb ^ qrow) & 7);
        Y[(size_t)qrow * C + cs * 8 + (col & 7)] = f2bf(o[j][dt][r] * inv);
      }
    }
  }
}

// ---------------------------------------------------------------------------
extern "C" void kernel_launch(void* const* d_in, const int* in_sizes, int n_in,
                              void* d_out, int out_size, void* d_ws, size_t ws_size,
                              hipStream_t stream) {
  const float* x   = (const float*)d_in[0];
  const float* ref = (const float*)d_in[1];
  const float* Wq  = (const float*)d_in[2];
  const float* bq  = (const float*)d_in[3];
  const float* Wk  = (const float*)d_in[4];
  const float* bk  = (const float*)d_in[5];
  const float* Wv  = (const float*)d_in[6];
  const float* bv  = (const float*)d_in[7];
  const float* Wrk = (const float*)d_in[8];
  const float* brk = (const float*)d_in[9];
  const float* Wrv = (const float*)d_in[10];
  const float* brv = (const float*)d_in[11];
  const float* Wp  = (const float*)d_in[12];
  const float* bp  = (const float*)d_in[13];
  float* out = (float*)d_out;

  char* ws = (char*)d_ws;
  auto alloc = [&](size_t bytes) {
    char* p = ws; ws += (bytes + 255) & ~(size_t)255; return p;
  };
  const size_t WB = (size_t)1024 * 1024 * 2;
  unsigned short* Wqkv = (unsigned short*)alloc(3 * WB);
  unsigned short* Wrkv = (unsigned short*)alloc(2 * WB);
  unsigned short* WpT  = (unsigned short*)alloc(WB);
  unsigned short* xg  = (unsigned short*)alloc((size_t)10240 * 1024 * 2);
  unsigned short* rg  = xg + (size_t)8192 * 1024;
  unsigned short* qb  = (unsigned short*)alloc((size_t)8192 * 1024 * 2);
  unsigned short* kb  = (unsigned short*)alloc((size_t)4 * 2560 * 1024 * 2);
  unsigned short* vbT = (unsigned short*)alloc((size_t)4096 * 2560 * 2);
  unsigned short* yb  = (unsigned short*)alloc((size_t)8192 * 1024 * 2);

  dim3 tb(256);

  W6 wp;
  wp.w[0] = Wq;  wp.o[0] = Wqkv;
  wp.w[1] = Wk;  wp.o[1] = Wqkv + (size_t)1024 * 1024;
  wp.w[2] = Wv;  wp.o[2] = Wqkv + (size_t)2048 * 1024;
  wp.w[3] = Wrk; wp.o[3] = Wrkv;
  wp.w[4] = Wrv; wp.o[4] = Wrkv + (size_t)1024 * 1024;
  wp.w[5] = Wp;  wp.o[5] = WpT;
  wtrans6<<<dim3(16, 16, 6), tb, 0, stream>>>(wp);

  convswz2<<<dim3(5120), tb, 0, stream>>>(x, ref, xg);

  gemm_bt<0><<<dim3(24, 64), tb, 0, stream>>>(xg, Wqkv, bq, bk, bv, qb, kb, vbT);
  gemm_bt<1><<<dim3(16, 16), tb, 0, stream>>>(rg, Wrkv, brk, brv, nullptr, kb, vbT, nullptr);

  attn<<<dim3(1024), tb, 0, stream>>>(qb, kb, vbT, yb);

  gemm_bt<2><<<dim3(8, 64), tb, 0, stream>>>(yb, WpT, bp, bp, bp, out, out, out);
}